// Round 8
// baseline (692.305 us; speedup 1.0000x reference)
//
#include <hip/hip_runtime.h>
#include <math.h>

#define N_NODES 100000
#define N_EDGES 3200000
#define N_GRAPHS 64
#define IN_DIM 128
#define HID 64
#define BN_EPS 1e-5f

#define PSHIFT 9
#define PBS 512
#define NPB ((N_NODES + PBS - 1) / PBS)  // 196
#define PART_BLOCKS 256
#define CHUNK_E (N_EDGES / PART_BLOCKS)  // 12500

#define QBOUND 25000
#define AGG_BLOCKS 2048

typedef unsigned short ushort_t;

__device__ __forceinline__ float bflo(unsigned u) { return __uint_as_float(u << 16); }
__device__ __forceinline__ float bfhi(unsigned u) { return __uint_as_float(u & 0xFFFF0000u); }
__device__ __forceinline__ unsigned f2bf(float f) {  // RNE
  unsigned u = __float_as_uint(f);
  return (u + 0x7FFFu + ((u >> 16) & 1u)) >> 16;
}

// ---------------- CSR build: two-level bucket sort (unchanged from r7) ----------------

__global__ __launch_bounds__(256) void ghist_k(const int* __restrict__ ei,
                                               int* __restrict__ gh) {
  __shared__ int h[NPB];
  for (int i = threadIdx.x; i < NPB; i += 256) h[i] = 0;
  __syncthreads();
  int stride = gridDim.x * 256;
  for (int e = blockIdx.x * 256 + threadIdx.x; e < N_EDGES; e += stride)
    atomicAdd(&h[ei[N_EDGES + e] >> PSHIFT], 1);
  __syncthreads();
  for (int i = threadIdx.x; i < NPB; i += 256) {
    int v = h[i];
    if (v) atomicAdd(&gh[i], v);
  }
}

__global__ __launch_bounds__(256) void gscan_k(const int* __restrict__ gh,
                                               int* __restrict__ boff,
                                               int* __restrict__ gcur) {
  __shared__ int sa[256], sb[256];
  int t = threadIdx.x;
  int v = (t < NPB) ? gh[t] : 0;
  sa[t] = v;
  __syncthreads();
  int* src = sa; int* dst = sb;
  for (int o = 1; o < 256; o <<= 1) {
    dst[t] = src[t] + ((t >= o) ? src[t - o] : 0);
    __syncthreads();
    int* tmp = src; src = dst; dst = tmp;
  }
  if (t < NPB) {
    int excl = src[t] - v;
    boff[t] = excl;
    gcur[t] = excl;
    if (t == NPB - 1) boff[NPB] = src[t];
  }
}

__global__ __launch_bounds__(512) void part_k(const int* __restrict__ ei,
                                              int* __restrict__ gcur,
                                              unsigned* __restrict__ tmp) {
  __shared__ int lh[NPB];
  __shared__ int lcur[NPB];
  int t = threadIdx.x;
  for (int i = t; i < NPB; i += 512) lh[i] = 0;
  __syncthreads();
  int c0 = blockIdx.x * CHUNK_E;
  int c1 = c0 + CHUNK_E;
  for (int e = c0 + t; e < c1; e += 512)
    atomicAdd(&lh[ei[N_EDGES + e] >> PSHIFT], 1);
  __syncthreads();
  for (int i = t; i < NPB; i += 512) {
    int v = lh[i];
    lcur[i] = v ? atomicAdd(&gcur[i], v) : 0;
  }
  __syncthreads();
  for (int e = c0 + t; e < c1; e += 512) {
    int dst = ei[N_EDGES + e];
    int src = ei[e];
    int b = dst >> PSHIFT;
    int p = atomicAdd(&lcur[b], 1);
    tmp[p] = ((unsigned)(dst & (PBS - 1)) << 17) | (unsigned)src;
  }
}

// fused per-bucket: histogram per (node, src-quartile) -> rp4/dinv -> place
__global__ __launch_bounds__(512) void bwork_k(
    const unsigned* __restrict__ tmp, const int* __restrict__ boff,
    int* __restrict__ rp4, float* __restrict__ dinv, int* __restrict__ csr) {
  int b = blockIdx.x;
  int base = boff[b], end = boff[b + 1];
  int t = threadIdx.x;
  __shared__ int cnt[PBS * 4];
  __shared__ int cur[PBS * 4];
  __shared__ int sa[PBS], sb[PBS];
  for (int i = t; i < PBS * 4; i += 512) cnt[i] = 0;
  __syncthreads();
  for (int i = base + t; i < end; i += 512) {
    unsigned u = tmp[i];
    int nl = u >> 17;
    int src = u & 0x1FFFF;
    int qq = (src >= QBOUND) + (src >= 2 * QBOUND) + (src >= 3 * QBOUND);
    atomicAdd(&cnt[nl * 4 + qq], 1);
  }
  __syncthreads();
  int c0 = cnt[t * 4], c1 = cnt[t * 4 + 1], c2 = cnt[t * 4 + 2], c3 = cnt[t * 4 + 3];
  int tsum = c0 + c1 + c2 + c3;
  sa[t] = tsum;
  __syncthreads();
  int* src_ = sa; int* dst_ = sb;
  for (int o = 1; o < PBS; o <<= 1) {
    dst_[t] = src_[t] + ((t >= o) ? src_[t - o] : 0);
    __syncthreads();
    int* z = src_; src_ = dst_; dst_ = z;
  }
  int nb = src_[t] - tsum;  // exclusive node base within bucket
  int o0 = nb, o1 = nb + c0, o2 = nb + c0 + c1, o3 = nb + c0 + c1 + c2;
  cur[t * 4] = o0; cur[t * 4 + 1] = o1; cur[t * 4 + 2] = o2; cur[t * 4 + 3] = o3;
  int n = b * PBS + t;
  if (n < N_NODES) {
    rp4[4 * n] = base + o0;
    rp4[4 * n + 1] = base + o1;
    rp4[4 * n + 2] = base + o2;
    rp4[4 * n + 3] = base + o3;
    dinv[n] = rsqrtf((float)(tsum + 1));  // +1 self loop
    if (n == N_NODES - 1) rp4[4 * N_NODES] = base + nb + tsum;
  }
  __syncthreads();
  for (int i = base + t; i < end; i += 512) {
    unsigned u = tmp[i];
    int nl = u >> 17;
    int src = u & 0x1FFFF;
    int qq = (src >= QBOUND) + (src >= 2 * QBOUND) + (src >= 3 * QBOUND);
    int p = atomicAdd(&cur[nl * 4 + qq], 1);
    csr[base + p] = src << 7;  // byte offset into bf16 hs
  }
}

// ---------------- GEMM: hs[n][c] = dinv[n] * (BN(X)[n] @ W)[c] -> bf16 ----------------

template <int K, bool APPLY, bool RELU>
__global__ __launch_bounds__(256) void gemm_k(
    const float* __restrict__ X, const float* __restrict__ W,
    const float* __restrict__ scale, const float* __restrict__ shift,
    const float* __restrict__ dinv, ushort_t* __restrict__ out, int nrows) {
  constexpr int WROW = K + 1;
  __shared__ float wt[64 * WROW];   // wt[c][k]  (W transposed)
  __shared__ float xs[64 * 68];     // xs[r][k]
  const int tid = threadIdx.x;
  const int tc = tid & 15;
  const int tr = tid >> 4;

  for (int idx = tid; idx < K * 64; idx += 256) {
    int k = idx >> 6, c = idx & 63;
    wt[c * WROW + k] = W[idx];
  }

  const int rowbase = blockIdx.x * 64;
  float acc[4][4] = {};

  for (int kc = 0; kc < K; kc += 64) {
    __syncthreads();
    {
      const int kq = tid & 15;
      const int rr = tid >> 4;
#pragma unroll
      for (int p = 0; p < 4; ++p) {
        int r = rr + p * 16;
        int grow = rowbase + r;
        float4 v = make_float4(0.f, 0.f, 0.f, 0.f);
        if (grow < nrows) v = *(const float4*)(X + (size_t)grow * K + kc + kq * 4);
        if (APPLY) {
          int kg = kc + kq * 4;
          float4 sc = *(const float4*)(scale + kg);
          float4 sh = *(const float4*)(shift + kg);
          v.x = v.x * sc.x + sh.x;
          v.y = v.y * sc.y + sh.y;
          v.z = v.z * sc.z + sh.z;
          v.w = v.w * sc.w + sh.w;
          if (RELU) {
            v.x = fmaxf(v.x, 0.f); v.y = fmaxf(v.y, 0.f);
            v.z = fmaxf(v.z, 0.f); v.w = fmaxf(v.w, 0.f);
          }
        }
        *(float4*)(xs + r * 68 + kq * 4) = v;
      }
    }
    __syncthreads();
#pragma unroll 4
    for (int k0 = 0; k0 < 64; k0 += 4) {
      float4 xv[4], wv[4];
#pragma unroll
      for (int i = 0; i < 4; ++i)
        xv[i] = *(const float4*)(xs + (tr * 4 + i) * 68 + k0);
#pragma unroll
      for (int j = 0; j < 4; ++j)
        wv[j] = *(const float4*)(wt + (4 * tc + j) * WROW + kc + k0);
#pragma unroll
      for (int i = 0; i < 4; ++i)
#pragma unroll
        for (int j = 0; j < 4; ++j)
          acc[i][j] += xv[i].x * wv[j].x + xv[i].y * wv[j].y +
                       xv[i].z * wv[j].z + xv[i].w * wv[j].w;
    }
  }

  char* ob = (char*)out;
#pragma unroll
  for (int i = 0; i < 4; ++i) {
    int grow = rowbase + tr * 4 + i;
    if (grow < nrows) {
      float dn = dinv[grow];
      uint2 o;
      o.x = f2bf(acc[i][0] * dn) | (f2bf(acc[i][1] * dn) << 16);
      o.y = f2bf(acc[i][2] * dn) | (f2bf(acc[i][3] * dn) << 16);
      *(uint2*)(ob + (size_t)grow * 128 + tc * 8) = o;
    }
  }
}

// ---------------- wave-per-node aggregation + fused BN stats ----------------
// out[d] = dinv[d]*(sum_src hs[src] + hs[d]) + bias. One wave per node:
// lane = (slot g=lane>>3, oct q=lane&7). 8 slots x uint4 = 8 rows per VMEM
// instruction; unroll x2 with separate acc chains -> 16 rows in flight.
// Loop bounds wave-uniform (no divergence); slot reduce via shfl_xor.

__global__ __launch_bounds__(256) void agg_k(
    const ushort_t* __restrict__ hs, const float* __restrict__ dinv,
    const int* __restrict__ rp4, const int* __restrict__ csr,
    const float* __restrict__ bias, float* __restrict__ out,
    float* __restrict__ sums) {
  const int tid = threadIdx.x;
  const int w = tid >> 6;
  const int lane = tid & 63;
  const int g = lane >> 3;     // edge slot 0..7
  const int q = lane & 7;      // feature oct: features 8q..8q+7
  const char* hb = (const char*)hs;

  float4 b0 = *(const float4*)(bias + q * 8);
  float4 b1 = *(const float4*)(bias + q * 8 + 4);

  float4 st0 = {0,0,0,0}, st1 = {0,0,0,0};
  float4 sq0 = {0,0,0,0}, sq1 = {0,0,0,0};

  for (int n = blockIdx.x * 4 + w; n < N_NODES; n += AGG_BLOCKS * 4) {
    int r0 = rp4[4 * n];
    int cnt = rp4[4 * n + 4] - r0;
    float4 aA0 = {0,0,0,0}, aA1 = {0,0,0,0};
    float4 aB0 = {0,0,0,0}, aB1 = {0,0,0,0};
    int i = 0;
    for (; i + 16 <= cnt; i += 16) {
      int e0 = csr[r0 + i + g];
      int e1 = csr[r0 + i + 8 + g];
      uint4 v0 = *(const uint4*)(hb + (size_t)(unsigned)e0 + (q << 4));
      uint4 v1 = *(const uint4*)(hb + (size_t)(unsigned)e1 + (q << 4));
      aA0.x += bflo(v0.x); aA0.y += bfhi(v0.x);
      aA0.z += bflo(v0.y); aA0.w += bfhi(v0.y);
      aA1.x += bflo(v0.z); aA1.y += bfhi(v0.z);
      aA1.z += bflo(v0.w); aA1.w += bfhi(v0.w);
      aB0.x += bflo(v1.x); aB0.y += bfhi(v1.x);
      aB0.z += bflo(v1.y); aB0.w += bfhi(v1.y);
      aB1.x += bflo(v1.z); aB1.y += bfhi(v1.z);
      aB1.z += bflo(v1.w); aB1.w += bfhi(v1.w);
    }
    for (; i + 8 <= cnt; i += 8) {
      int e0 = csr[r0 + i + g];
      uint4 v0 = *(const uint4*)(hb + (size_t)(unsigned)e0 + (q << 4));
      aA0.x += bflo(v0.x); aA0.y += bfhi(v0.x);
      aA0.z += bflo(v0.y); aA0.w += bfhi(v0.y);
      aA1.x += bflo(v0.z); aA1.y += bfhi(v0.z);
      aA1.z += bflo(v0.w); aA1.w += bfhi(v0.w);
    }
    if (i + g < cnt) {  // tail: single partially-active iteration
      int e0 = csr[r0 + i + g];
      uint4 v0 = *(const uint4*)(hb + (size_t)(unsigned)e0 + (q << 4));
      aB0.x += bflo(v0.x); aB0.y += bfhi(v0.x);
      aB0.z += bflo(v0.y); aB0.w += bfhi(v0.y);
      aB1.x += bflo(v0.z); aB1.y += bfhi(v0.z);
      aB1.z += bflo(v0.w); aB1.w += bfhi(v0.w);
    }
    float4 a0, a1;
    a0.x = aA0.x + aB0.x; a0.y = aA0.y + aB0.y;
    a0.z = aA0.z + aB0.z; a0.w = aA0.w + aB0.w;
    a1.x = aA1.x + aB1.x; a1.y = aA1.y + aB1.y;
    a1.z = aA1.z + aB1.z; a1.w = aA1.w + aB1.w;
    // reduce across 8 slots
#pragma unroll
    for (int o = 8; o < 64; o <<= 1) {
      a0.x += __shfl_xor(a0.x, o); a0.y += __shfl_xor(a0.y, o);
      a0.z += __shfl_xor(a0.z, o); a0.w += __shfl_xor(a0.w, o);
      a1.x += __shfl_xor(a1.x, o); a1.y += __shfl_xor(a1.y, o);
      a1.z += __shfl_xor(a1.z, o); a1.w += __shfl_xor(a1.w, o);
    }
    // self loop + scale + bias
    uint4 sv = *(const uint4*)(hb + ((size_t)n << 7) + (q << 4));
    a0.x += bflo(sv.x); a0.y += bfhi(sv.x);
    a0.z += bflo(sv.y); a0.w += bfhi(sv.y);
    a1.x += bflo(sv.z); a1.y += bfhi(sv.z);
    a1.z += bflo(sv.w); a1.w += bfhi(sv.w);
    float dn = dinv[n];
    a0.x = a0.x * dn + b0.x; a0.y = a0.y * dn + b0.y;
    a0.z = a0.z * dn + b0.z; a0.w = a0.w * dn + b0.w;
    a1.x = a1.x * dn + b1.x; a1.y = a1.y * dn + b1.y;
    a1.z = a1.z * dn + b1.z; a1.w = a1.w * dn + b1.w;
    if (g == 0) {
      *(float4*)(out + ((size_t)n << 6) + q * 8) = a0;
      *(float4*)(out + ((size_t)n << 6) + q * 8 + 4) = a1;
      st0.x += a0.x; st0.y += a0.y; st0.z += a0.z; st0.w += a0.w;
      st1.x += a1.x; st1.y += a1.y; st1.z += a1.z; st1.w += a1.w;
      sq0.x += a0.x * a0.x; sq0.y += a0.y * a0.y;
      sq0.z += a0.z * a0.z; sq0.w += a0.w * a0.w;
      sq1.x += a1.x * a1.x; sq1.y += a1.y * a1.y;
      sq1.z += a1.z * a1.z; sq1.w += a1.w * a1.w;
    }
  }

  __shared__ float rs[4][64], rs2[4][64];
  if (g == 0) {
    *(float4*)(&rs[w][q * 8]) = st0;  *(float4*)(&rs[w][q * 8 + 4]) = st1;
    *(float4*)(&rs2[w][q * 8]) = sq0; *(float4*)(&rs2[w][q * 8 + 4]) = sq1;
  }
  __syncthreads();
  if (tid < 64) {
    atomicAdd(&sums[tid], rs[0][tid] + rs[1][tid] + rs[2][tid] + rs[3][tid]);
  } else if (tid < 128) {
    int c = tid - 64;
    atomicAdd(&sums[64 + c], rs2[0][c] + rs2[1][c] + rs2[2][c] + rs2[3][c]);
  }
}

__global__ void bnfinal_k(const float* __restrict__ sums,
                          const float* __restrict__ gamma, const float* __restrict__ beta,
                          float* __restrict__ scale, float* __restrict__ shift) {
  int c = threadIdx.x;  // 64 threads
  float mean = sums[c] / (float)N_NODES;
  float var = sums[64 + c] / (float)N_NODES - mean * mean;
  float sc = gamma[c] * rsqrtf(var + BN_EPS);
  scale[c] = sc;
  shift[c] = beta[c] - mean * sc;
}

// ---------------- pooling (batch is sorted) ----------------

#define POOL_CHUNK 32
__global__ __launch_bounds__(64) void pool_k(
    const float* __restrict__ h, const float* __restrict__ scale,
    const float* __restrict__ shift, const int* __restrict__ batch,
    float* __restrict__ psum, float* __restrict__ pcnt) {
  int lane = threadIdx.x;
  int start = blockIdx.x * POOL_CHUNK;
  if (start >= N_NODES) return;
  int end = min(start + POOL_CHUNK, N_NODES);
  float sc = scale[lane], sh = shift[lane];
  float acc = 0.f, cnt = 0.f;
  int cur = batch[start];
  for (int n = start; n < end; ++n) {
    int g = batch[n];
    if (g != cur) {
      atomicAdd(&psum[cur * 64 + lane], acc);
      if (lane == 0) atomicAdd(&pcnt[cur], cnt);
      acc = 0.f; cnt = 0.f; cur = g;
    }
    acc += h[(size_t)n * 64 + lane] * sc + sh;
    cnt += 1.f;
  }
  atomicAdd(&psum[cur * 64 + lane], acc);
  if (lane == 0) atomicAdd(&pcnt[cur], cnt);
}

// ---------------- centroid classifier ----------------

__global__ void classify_k(const float* __restrict__ psum, const float* __restrict__ pcnt,
                           const float* __restrict__ cg_, const float* __restrict__ cm,
                           const float* __restrict__ temp, float* __restrict__ out) {
  int g = blockIdx.x;
  int t = threadIdx.x;
  __shared__ float emb[64];
  __shared__ float dist[208];
  if (t < 64) emb[t] = psum[g * 64 + t] / fmaxf(pcnt[g], 1.0f);
  __syncthreads();
  if (t < 197) {
    const float* C = (t < 5) ? (cg_ + t * 64) : (cm + (t - 5) * 64);
    float d = 0.f;
#pragma unroll 8
    for (int k = 0; k < 64; ++k) {
      float df = emb[k] - C[k];
      d += df * df;
    }
    dist[t] = d;
  }
  __syncthreads();
  float tv = temp[0];
  if (t == 64) {
    float m = dist[0];
    for (int j = 1; j < 5; ++j) m = fminf(m, dist[j]);
    out[g * 65] = -m / tv;
  }
  if (t < 64) {
    float m = fminf(dist[5 + t * 3], fminf(dist[5 + t * 3 + 1], dist[5 + t * 3 + 2]));
    out[g * 65 + 1 + t] = -m / tv;
  }
}

// ---------------- launch ----------------

extern "C" void kernel_launch(void* const* d_in, const int* in_sizes, int n_in,
                              void* d_out, int out_size, void* d_ws, size_t ws_size,
                              hipStream_t stream) {
  const float* x   = (const float*)d_in[0];
  const int* ei    = (const int*)d_in[1];
  const int* batch = (const int*)d_in[2];
  const float* W1 = (const float*)d_in[3];  const float* b1 = (const float*)d_in[4];
  const float* g1 = (const float*)d_in[5];  const float* be1 = (const float*)d_in[6];
  const float* W2 = (const float*)d_in[7];  const float* b2 = (const float*)d_in[8];
  const float* g2 = (const float*)d_in[9];  const float* be2 = (const float*)d_in[10];
  const float* W3 = (const float*)d_in[11]; const float* b3 = (const float*)d_in[12];
  const float* g3 = (const float*)d_in[13]; const float* be3 = (const float*)d_in[14];
  const float* cg_ = (const float*)d_in[15];
  const float* cm = (const float*)d_in[16];
  const float* temp = (const float*)d_in[17];
  float* out = (float*)d_out;

  char* ws = (char*)d_ws;
  size_t off = 0;
  auto alloc = [&](size_t bytes) -> void* {
    void* p = ws + off;
    off = (off + bytes + 255) & ~(size_t)255;
    return p;
  };
  int* gh        = (int*)alloc((size_t)NPB * 4);
  int* boff      = (int*)alloc((size_t)(NPB + 1) * 4);
  int* gcur      = (int*)alloc((size_t)NPB * 4);
  unsigned* tmp  = (unsigned*)alloc((size_t)N_EDGES * 4);
  int* csr       = (int*)alloc((size_t)N_EDGES * 4);
  int* rp4       = (int*)alloc((size_t)(4 * N_NODES + 1) * 4);
  float* dinv    = (float*)alloc((size_t)N_NODES * 4);
  ushort_t* hA   = (ushort_t*)alloc((size_t)N_NODES * 64 * 2);  // bf16 hs
  float* hB      = (float*)alloc((size_t)N_NODES * 64 * 4);
  float* sumsAll = (float*)alloc(3 * 128 * 4);
  float* scale   = (float*)alloc(64 * 4);
  float* shift   = (float*)alloc(64 * 4);
  float* psum    = (float*)alloc(64 * 64 * 4);
  float* pcnt    = (float*)alloc(64 * 4);

  hipMemsetAsync(gh, 0, (size_t)NPB * 4, stream);
  hipMemsetAsync(sumsAll, 0, 3 * 128 * 4, stream);
  hipMemsetAsync(psum, 0, 64 * 64 * 4, stream);
  hipMemsetAsync(pcnt, 0, 64 * 4, stream);

  const int NB_GEMM = (N_NODES + 63) / 64;   // 1563
  const int NB_POOL = (N_NODES + POOL_CHUNK - 1) / POOL_CHUNK;

  // CSR build
  ghist_k<<<512, 256, 0, stream>>>(ei, gh);
  gscan_k<<<1, 256, 0, stream>>>(gh, boff, gcur);
  part_k<<<PART_BLOCKS, 512, 0, stream>>>(ei, gcur, tmp);
  bwork_k<<<NPB, 512, 0, stream>>>(tmp, boff, rp4, dinv, csr);

  // layer 1
  gemm_k<IN_DIM, false, false><<<NB_GEMM, 256, 0, stream>>>(x, W1, nullptr, nullptr, dinv, hA, N_NODES);
  agg_k<<<AGG_BLOCKS, 256, 0, stream>>>(hA, dinv, rp4, csr, b1, hB, sumsAll);
  bnfinal_k<<<1, 64, 0, stream>>>(sumsAll, g1, be1, scale, shift);

  // layer 2
  gemm_k<HID, true, true><<<NB_GEMM, 256, 0, stream>>>(hB, W2, scale, shift, dinv, hA, N_NODES);
  agg_k<<<AGG_BLOCKS, 256, 0, stream>>>(hA, dinv, rp4, csr, b2, hB, sumsAll + 128);
  bnfinal_k<<<1, 64, 0, stream>>>(sumsAll + 128, g2, be2, scale, shift);

  // layer 3
  gemm_k<HID, true, true><<<NB_GEMM, 256, 0, stream>>>(hB, W3, scale, shift, dinv, hA, N_NODES);
  agg_k<<<AGG_BLOCKS, 256, 0, stream>>>(hA, dinv, rp4, csr, b3, hB, sumsAll + 256);
  bnfinal_k<<<1, 64, 0, stream>>>(sumsAll + 256, g3, be3, scale, shift);

  // pool (BN3 applied here) + classify
  pool_k<<<NB_POOL, 64, 0, stream>>>(hB, scale, shift, batch, psum, pcnt);
  classify_k<<<N_GRAPHS, 256, 0, stream>>>(psum, pcnt, cg_, cm, temp, out);
}

// Round 9
// 600.749 us; speedup vs baseline: 1.1524x; 1.1524x over previous
//
#include <hip/hip_runtime.h>
#include <math.h>

#define N_NODES 100000
#define N_EDGES 3200000
#define N_GRAPHS 64
#define IN_DIM 128
#define HID 64
#define BN_EPS 1e-5f

#define PSHIFT 9
#define PBS 512
#define NPB ((N_NODES + PBS - 1) / PBS)  // 196
#define PART_BLOCKS 256
#define CHUNK_E (N_EDGES / PART_BLOCKS)  // 12500

#define QBOUND 25000
#define AGG_BLOCKS 2048

typedef unsigned short ushort_t;

__device__ __forceinline__ float bflo(unsigned u) { return __uint_as_float(u << 16); }
__device__ __forceinline__ float bfhi(unsigned u) { return __uint_as_float(u & 0xFFFF0000u); }
__device__ __forceinline__ unsigned f2bf(float f) {  // RNE
  unsigned u = __float_as_uint(f);
  return (u + 0x7FFFu + ((u >> 16) & 1u)) >> 16;
}

// ---------------- CSR build: two-level bucket sort (unchanged) ----------------

__global__ __launch_bounds__(256) void ghist_k(const int* __restrict__ ei,
                                               int* __restrict__ gh) {
  __shared__ int h[NPB];
  for (int i = threadIdx.x; i < NPB; i += 256) h[i] = 0;
  __syncthreads();
  int stride = gridDim.x * 256;
  for (int e = blockIdx.x * 256 + threadIdx.x; e < N_EDGES; e += stride)
    atomicAdd(&h[ei[N_EDGES + e] >> PSHIFT], 1);
  __syncthreads();
  for (int i = threadIdx.x; i < NPB; i += 256) {
    int v = h[i];
    if (v) atomicAdd(&gh[i], v);
  }
}

__global__ __launch_bounds__(256) void gscan_k(const int* __restrict__ gh,
                                               int* __restrict__ boff,
                                               int* __restrict__ gcur) {
  __shared__ int sa[256], sb[256];
  int t = threadIdx.x;
  int v = (t < NPB) ? gh[t] : 0;
  sa[t] = v;
  __syncthreads();
  int* src = sa; int* dst = sb;
  for (int o = 1; o < 256; o <<= 1) {
    dst[t] = src[t] + ((t >= o) ? src[t - o] : 0);
    __syncthreads();
    int* tmp = src; src = dst; dst = tmp;
  }
  if (t < NPB) {
    int excl = src[t] - v;
    boff[t] = excl;
    gcur[t] = excl;
    if (t == NPB - 1) boff[NPB] = src[t];
  }
}

__global__ __launch_bounds__(512) void part_k(const int* __restrict__ ei,
                                              int* __restrict__ gcur,
                                              unsigned* __restrict__ tmp) {
  __shared__ int lh[NPB];
  __shared__ int lcur[NPB];
  int t = threadIdx.x;
  for (int i = t; i < NPB; i += 512) lh[i] = 0;
  __syncthreads();
  int c0 = blockIdx.x * CHUNK_E;
  int c1 = c0 + CHUNK_E;
  for (int e = c0 + t; e < c1; e += 512)
    atomicAdd(&lh[ei[N_EDGES + e] >> PSHIFT], 1);
  __syncthreads();
  for (int i = t; i < NPB; i += 512) {
    int v = lh[i];
    lcur[i] = v ? atomicAdd(&gcur[i], v) : 0;
  }
  __syncthreads();
  for (int e = c0 + t; e < c1; e += 512) {
    int dst = ei[N_EDGES + e];
    int src = ei[e];
    int b = dst >> PSHIFT;
    int p = atomicAdd(&lcur[b], 1);
    tmp[p] = ((unsigned)(dst & (PBS - 1)) << 17) | (unsigned)src;
  }
}

// fused per-bucket: histogram per (node, src-quartile) -> rp4/dinv -> place
__global__ __launch_bounds__(512) void bwork_k(
    const unsigned* __restrict__ tmp, const int* __restrict__ boff,
    int* __restrict__ rp4, float* __restrict__ dinv, int* __restrict__ csr) {
  int b = blockIdx.x;
  int base = boff[b], end = boff[b + 1];
  int t = threadIdx.x;
  __shared__ int cnt[PBS * 4];
  __shared__ int cur[PBS * 4];
  __shared__ int sa[PBS], sb[PBS];
  for (int i = t; i < PBS * 4; i += 512) cnt[i] = 0;
  __syncthreads();
  for (int i = base + t; i < end; i += 512) {
    unsigned u = tmp[i];
    int nl = u >> 17;
    int src = u & 0x1FFFF;
    int qq = (src >= QBOUND) + (src >= 2 * QBOUND) + (src >= 3 * QBOUND);
    atomicAdd(&cnt[nl * 4 + qq], 1);
  }
  __syncthreads();
  int c0 = cnt[t * 4], c1 = cnt[t * 4 + 1], c2 = cnt[t * 4 + 2], c3 = cnt[t * 4 + 3];
  int tsum = c0 + c1 + c2 + c3;
  sa[t] = tsum;
  __syncthreads();
  int* src_ = sa; int* dst_ = sb;
  for (int o = 1; o < PBS; o <<= 1) {
    dst_[t] = src_[t] + ((t >= o) ? src_[t - o] : 0);
    __syncthreads();
    int* z = src_; src_ = dst_; dst_ = z;
  }
  int nb = src_[t] - tsum;  // exclusive node base within bucket
  int o0 = nb, o1 = nb + c0, o2 = nb + c0 + c1, o3 = nb + c0 + c1 + c2;
  cur[t * 4] = o0; cur[t * 4 + 1] = o1; cur[t * 4 + 2] = o2; cur[t * 4 + 3] = o3;
  int n = b * PBS + t;
  if (n < N_NODES) {
    rp4[4 * n] = base + o0;
    rp4[4 * n + 1] = base + o1;
    rp4[4 * n + 2] = base + o2;
    rp4[4 * n + 3] = base + o3;
    dinv[n] = rsqrtf((float)(tsum + 1));  // +1 self loop
    if (n == N_NODES - 1) rp4[4 * N_NODES] = base + nb + tsum;
  }
  __syncthreads();
  for (int i = base + t; i < end; i += 512) {
    unsigned u = tmp[i];
    int nl = u >> 17;
    int src = u & 0x1FFFF;
    int qq = (src >= QBOUND) + (src >= 2 * QBOUND) + (src >= 3 * QBOUND);
    int p = atomicAdd(&cur[nl * 4 + qq], 1);
    csr[base + p] = src << 7;  // byte offset into bf16 hs
  }
}

// ---------------- GEMM: hs[n][c] = dinv[n] * (BN(X)[n] @ W)[c] -> bf16 ----------------
// APPLY path computes BN scale/shift inline from raw sums (no bnfinal kernel).

template <int K, bool APPLY, bool RELU>
__global__ __launch_bounds__(256) void gemm_k(
    const float* __restrict__ X, const float* __restrict__ W,
    const float* __restrict__ sums, const float* __restrict__ gamma,
    const float* __restrict__ beta,
    const float* __restrict__ dinv, ushort_t* __restrict__ out, int nrows) {
  constexpr int WROW = K + 1;
  __shared__ float wt[64 * WROW];   // wt[c][k]  (W transposed)
  __shared__ float xs[64 * 68];     // xs[r][k]
  const int tid = threadIdx.x;
  const int tc = tid & 15;
  const int tr = tid >> 4;

  // inline BN coefficients for this thread's staging quad (K=64 path only)
  float sc4[4], sh4[4];
  if (APPLY) {
    const int kq = tid & 15;
#pragma unroll
    for (int t = 0; t < 4; ++t) {
      int kg = kq * 4 + t;
      float m = sums[kg] / (float)N_NODES;
      float v = sums[64 + kg] / (float)N_NODES - m * m;
      float s = gamma[kg] * rsqrtf(v + BN_EPS);
      sc4[t] = s;
      sh4[t] = beta[kg] - m * s;
    }
  }

  for (int idx = tid; idx < K * 64; idx += 256) {
    int k = idx >> 6, c = idx & 63;
    wt[c * WROW + k] = W[idx];
  }

  const int rowbase = blockIdx.x * 64;
  float acc[4][4] = {};

  for (int kc = 0; kc < K; kc += 64) {
    __syncthreads();
    {
      const int kq = tid & 15;
      const int rr = tid >> 4;
#pragma unroll
      for (int p = 0; p < 4; ++p) {
        int r = rr + p * 16;
        int grow = rowbase + r;
        float4 v = make_float4(0.f, 0.f, 0.f, 0.f);
        if (grow < nrows) v = *(const float4*)(X + (size_t)grow * K + kc + kq * 4);
        if (APPLY) {
          v.x = v.x * sc4[0] + sh4[0];
          v.y = v.y * sc4[1] + sh4[1];
          v.z = v.z * sc4[2] + sh4[2];
          v.w = v.w * sc4[3] + sh4[3];
          if (RELU) {
            v.x = fmaxf(v.x, 0.f); v.y = fmaxf(v.y, 0.f);
            v.z = fmaxf(v.z, 0.f); v.w = fmaxf(v.w, 0.f);
          }
        }
        *(float4*)(xs + r * 68 + kq * 4) = v;
      }
    }
    __syncthreads();
#pragma unroll 4
    for (int k0 = 0; k0 < 64; k0 += 4) {
      float4 xv[4], wv[4];
#pragma unroll
      for (int i = 0; i < 4; ++i)
        xv[i] = *(const float4*)(xs + (tr * 4 + i) * 68 + k0);
#pragma unroll
      for (int j = 0; j < 4; ++j)
        wv[j] = *(const float4*)(wt + (4 * tc + j) * WROW + kc + k0);
#pragma unroll
      for (int i = 0; i < 4; ++i)
#pragma unroll
        for (int j = 0; j < 4; ++j)
          acc[i][j] += xv[i].x * wv[j].x + xv[i].y * wv[j].y +
                       xv[i].z * wv[j].z + xv[i].w * wv[j].w;
    }
  }

  char* ob = (char*)out;
#pragma unroll
  for (int i = 0; i < 4; ++i) {
    int grow = rowbase + tr * 4 + i;
    if (grow < nrows) {
      float dn = dinv[grow];
      uint2 o;
      o.x = f2bf(acc[i][0] * dn) | (f2bf(acc[i][1] * dn) << 16);
      o.y = f2bf(acc[i][2] * dn) | (f2bf(acc[i][3] * dn) << 16);
      *(uint2*)(ob + (size_t)grow * 128 + tc * 8) = o;
    }
  }
}

// ---------------- aggregation: r5 structure + x8 unroll + fused BN stats ----------------
// 16 lanes per node (4 nodes per wave), uint2 bf16 gathers, 8 gathers in
// flight per group (two independent accumulator chains).

__global__ __launch_bounds__(256) void agg_k(
    const ushort_t* __restrict__ hs, const float* __restrict__ dinv,
    const int* __restrict__ rp4, const int* __restrict__ csr,
    const float* __restrict__ bias, float* __restrict__ out,
    float* __restrict__ sums) {
  const int tid = threadIdx.x;
  const int w = tid >> 6;
  const int lane = tid & 63;
  const int g = lane >> 4;     // node slot 0..3
  const int q = lane & 15;     // feature quad
  const char* hb = (const char*)hs;

  float4 bval = *(const float4*)(bias + q * 4);
  float4 s = make_float4(0.f, 0.f, 0.f, 0.f);
  float4 s2 = make_float4(0.f, 0.f, 0.f, 0.f);

  for (int n = blockIdx.x * 16 + w * 4 + g; n < N_NODES; n += AGG_BLOCKS * 16) {
    int r0 = rp4[4 * n];
    int cnt = rp4[4 * n + 4] - r0;
    float4 aA = {0, 0, 0, 0}, aB = {0, 0, 0, 0};
    int j = 0;
    for (; j + 8 <= cnt; j += 8) {
      int e0 = csr[r0 + j + 0], e1 = csr[r0 + j + 1];
      int e2 = csr[r0 + j + 2], e3 = csr[r0 + j + 3];
      int e4 = csr[r0 + j + 4], e5 = csr[r0 + j + 5];
      int e6 = csr[r0 + j + 6], e7 = csr[r0 + j + 7];
      uint2 v0 = *(const uint2*)(hb + (size_t)(unsigned)e0 + (q << 3));
      uint2 v1 = *(const uint2*)(hb + (size_t)(unsigned)e1 + (q << 3));
      uint2 v2 = *(const uint2*)(hb + (size_t)(unsigned)e2 + (q << 3));
      uint2 v3 = *(const uint2*)(hb + (size_t)(unsigned)e3 + (q << 3));
      uint2 v4 = *(const uint2*)(hb + (size_t)(unsigned)e4 + (q << 3));
      uint2 v5 = *(const uint2*)(hb + (size_t)(unsigned)e5 + (q << 3));
      uint2 v6 = *(const uint2*)(hb + (size_t)(unsigned)e6 + (q << 3));
      uint2 v7 = *(const uint2*)(hb + (size_t)(unsigned)e7 + (q << 3));
      aA.x += bflo(v0.x); aA.y += bfhi(v0.x); aA.z += bflo(v0.y); aA.w += bfhi(v0.y);
      aB.x += bflo(v1.x); aB.y += bfhi(v1.x); aB.z += bflo(v1.y); aB.w += bfhi(v1.y);
      aA.x += bflo(v2.x); aA.y += bfhi(v2.x); aA.z += bflo(v2.y); aA.w += bfhi(v2.y);
      aB.x += bflo(v3.x); aB.y += bfhi(v3.x); aB.z += bflo(v3.y); aB.w += bfhi(v3.y);
      aA.x += bflo(v4.x); aA.y += bfhi(v4.x); aA.z += bflo(v4.y); aA.w += bfhi(v4.y);
      aB.x += bflo(v5.x); aB.y += bfhi(v5.x); aB.z += bflo(v5.y); aB.w += bfhi(v5.y);
      aA.x += bflo(v6.x); aA.y += bfhi(v6.x); aA.z += bflo(v6.y); aA.w += bfhi(v6.y);
      aB.x += bflo(v7.x); aB.y += bfhi(v7.x); aB.z += bflo(v7.y); aB.w += bfhi(v7.y);
    }
    for (; j + 2 <= cnt; j += 2) {
      int e0 = csr[r0 + j + 0], e1 = csr[r0 + j + 1];
      uint2 v0 = *(const uint2*)(hb + (size_t)(unsigned)e0 + (q << 3));
      uint2 v1 = *(const uint2*)(hb + (size_t)(unsigned)e1 + (q << 3));
      aA.x += bflo(v0.x); aA.y += bfhi(v0.x); aA.z += bflo(v0.y); aA.w += bfhi(v0.y);
      aB.x += bflo(v1.x); aB.y += bfhi(v1.x); aB.z += bflo(v1.y); aB.w += bfhi(v1.y);
    }
    if (j < cnt) {
      int e0 = csr[r0 + j];
      uint2 v0 = *(const uint2*)(hb + (size_t)(unsigned)e0 + (q << 3));
      aA.x += bflo(v0.x); aA.y += bfhi(v0.x); aA.z += bflo(v0.y); aA.w += bfhi(v0.y);
    }
    // self row + finalize
    uint2 u = *(const uint2*)(hb + ((size_t)n << 7) + (q << 3));
    float4 a;
    a.x = aA.x + aB.x + bflo(u.x);
    a.y = aA.y + aB.y + bfhi(u.x);
    a.z = aA.z + aB.z + bflo(u.y);
    a.w = aA.w + aB.w + bfhi(u.y);
    float dn = dinv[n];
    a.x = a.x * dn + bval.x; a.y = a.y * dn + bval.y;
    a.z = a.z * dn + bval.z; a.w = a.w * dn + bval.w;
    *(float4*)(out + ((size_t)n << 6) + q * 4) = a;
    s.x += a.x; s.y += a.y; s.z += a.z; s.w += a.w;
    s2.x += a.x * a.x; s2.y += a.y * a.y;
    s2.z += a.z * a.z; s2.w += a.w * a.w;
  }

  __shared__ float rs[16][64];
  __shared__ float rs2[16][64];
  *(float4*)(&rs[w * 4 + g][q * 4]) = s;
  *(float4*)(&rs2[w * 4 + g][q * 4]) = s2;
  __syncthreads();
  int c = tid & 63;
  int r0_ = tid >> 6;
  float a = rs[r0_][c] + rs[r0_ + 4][c] + rs[r0_ + 8][c] + rs[r0_ + 12][c];
  float a2 = rs2[r0_][c] + rs2[r0_ + 4][c] + rs2[r0_ + 8][c] + rs2[r0_ + 12][c];
  __syncthreads();
  rs[r0_][c] = a;
  rs2[r0_][c] = a2;
  __syncthreads();
  if (r0_ == 0) {
    atomicAdd(&sums[c], rs[0][c] + rs[1][c] + rs[2][c] + rs[3][c]);
    atomicAdd(&sums[64 + c], rs2[0][c] + rs2[1][c] + rs2[2][c] + rs2[3][c]);
  }
}

// ---------------- pooling (batch is sorted); BN3 computed inline ----------------

#define POOL_CHUNK 32
__global__ __launch_bounds__(64) void pool_k(
    const float* __restrict__ h, const float* __restrict__ sums,
    const float* __restrict__ gamma, const float* __restrict__ beta,
    const int* __restrict__ batch,
    float* __restrict__ psum, float* __restrict__ pcnt) {
  int lane = threadIdx.x;
  int start = blockIdx.x * POOL_CHUNK;
  if (start >= N_NODES) return;
  int end = min(start + POOL_CHUNK, N_NODES);
  float m = sums[lane] / (float)N_NODES;
  float v = sums[64 + lane] / (float)N_NODES - m * m;
  float sc = gamma[lane] * rsqrtf(v + BN_EPS);
  float sh = beta[lane] - m * sc;
  float acc = 0.f, cnt = 0.f;
  int cur = batch[start];
  for (int n = start; n < end; ++n) {
    int g = batch[n];
    if (g != cur) {
      atomicAdd(&psum[cur * 64 + lane], acc);
      if (lane == 0) atomicAdd(&pcnt[cur], cnt);
      acc = 0.f; cnt = 0.f; cur = g;
    }
    acc += h[(size_t)n * 64 + lane] * sc + sh;
    cnt += 1.f;
  }
  atomicAdd(&psum[cur * 64 + lane], acc);
  if (lane == 0) atomicAdd(&pcnt[cur], cnt);
}

// ---------------- centroid classifier ----------------

__global__ void classify_k(const float* __restrict__ psum, const float* __restrict__ pcnt,
                           const float* __restrict__ cg_, const float* __restrict__ cm,
                           const float* __restrict__ temp, float* __restrict__ out) {
  int g = blockIdx.x;
  int t = threadIdx.x;
  __shared__ float emb[64];
  __shared__ float dist[208];
  if (t < 64) emb[t] = psum[g * 64 + t] / fmaxf(pcnt[g], 1.0f);
  __syncthreads();
  if (t < 197) {
    const float* C = (t < 5) ? (cg_ + t * 64) : (cm + (t - 5) * 64);
    float d = 0.f;
#pragma unroll 8
    for (int k = 0; k < 64; ++k) {
      float df = emb[k] - C[k];
      d += df * df;
    }
    dist[t] = d;
  }
  __syncthreads();
  float tv = temp[0];
  if (t == 64) {
    float m = dist[0];
    for (int j = 1; j < 5; ++j) m = fminf(m, dist[j]);
    out[g * 65] = -m / tv;
  }
  if (t < 64) {
    float m = fminf(dist[5 + t * 3], fminf(dist[5 + t * 3 + 1], dist[5 + t * 3 + 2]));
    out[g * 65 + 1 + t] = -m / tv;
  }
}

// ---------------- launch ----------------

extern "C" void kernel_launch(void* const* d_in, const int* in_sizes, int n_in,
                              void* d_out, int out_size, void* d_ws, size_t ws_size,
                              hipStream_t stream) {
  const float* x   = (const float*)d_in[0];
  const int* ei    = (const int*)d_in[1];
  const int* batch = (const int*)d_in[2];
  const float* W1 = (const float*)d_in[3];  const float* b1 = (const float*)d_in[4];
  const float* g1 = (const float*)d_in[5];  const float* be1 = (const float*)d_in[6];
  const float* W2 = (const float*)d_in[7];  const float* b2 = (const float*)d_in[8];
  const float* g2 = (const float*)d_in[9];  const float* be2 = (const float*)d_in[10];
  const float* W3 = (const float*)d_in[11]; const float* b3 = (const float*)d_in[12];
  const float* g3 = (const float*)d_in[13]; const float* be3 = (const float*)d_in[14];
  const float* cg_ = (const float*)d_in[15];
  const float* cm = (const float*)d_in[16];
  const float* temp = (const float*)d_in[17];
  float* out = (float*)d_out;

  char* ws = (char*)d_ws;
  size_t off = 0;
  auto alloc = [&](size_t bytes) -> void* {
    void* p = ws + off;
    off = (off + bytes + 255) & ~(size_t)255;
    return p;
  };
  int* gh        = (int*)alloc((size_t)NPB * 4);
  int* boff      = (int*)alloc((size_t)(NPB + 1) * 4);
  int* gcur      = (int*)alloc((size_t)NPB * 4);
  unsigned* tmp  = (unsigned*)alloc((size_t)N_EDGES * 4);
  int* csr       = (int*)alloc((size_t)N_EDGES * 4);
  int* rp4       = (int*)alloc((size_t)(4 * N_NODES + 1) * 4);
  float* dinv    = (float*)alloc((size_t)N_NODES * 4);
  ushort_t* hA   = (ushort_t*)alloc((size_t)N_NODES * 64 * 2);  // bf16 hs
  float* hB      = (float*)alloc((size_t)N_NODES * 64 * 4);
  float* sumsAll = (float*)alloc(3 * 128 * 4);
  float* psum    = (float*)alloc(64 * 64 * 4);
  float* pcnt    = (float*)alloc(64 * 4);

  hipMemsetAsync(gh, 0, (size_t)NPB * 4, stream);
  hipMemsetAsync(sumsAll, 0, 3 * 128 * 4, stream);
  hipMemsetAsync(psum, 0, 64 * 64 * 4, stream);
  hipMemsetAsync(pcnt, 0, 64 * 4, stream);

  const int NB_GEMM = (N_NODES + 63) / 64;   // 1563
  const int NB_POOL = (N_NODES + POOL_CHUNK - 1) / POOL_CHUNK;

  // CSR build
  ghist_k<<<512, 256, 0, stream>>>(ei, gh);
  gscan_k<<<1, 256, 0, stream>>>(gh, boff, gcur);
  part_k<<<PART_BLOCKS, 512, 0, stream>>>(ei, gcur, tmp);
  bwork_k<<<NPB, 512, 0, stream>>>(tmp, boff, rp4, dinv, csr);

  // layer 1
  gemm_k<IN_DIM, false, false><<<NB_GEMM, 256, 0, stream>>>(x, W1, nullptr, nullptr, nullptr, dinv, hA, N_NODES);
  agg_k<<<AGG_BLOCKS, 256, 0, stream>>>(hA, dinv, rp4, csr, b1, hB, sumsAll);

  // layer 2 (BN1+ReLU inline from sums)
  gemm_k<HID, true, true><<<NB_GEMM, 256, 0, stream>>>(hB, W2, sumsAll, g1, be1, dinv, hA, N_NODES);
  agg_k<<<AGG_BLOCKS, 256, 0, stream>>>(hA, dinv, rp4, csr, b2, hB, sumsAll + 128);

  // layer 3 (BN2+ReLU inline from sums)
  gemm_k<HID, true, true><<<NB_GEMM, 256, 0, stream>>>(hB, W3, sumsAll + 128, g2, be2, dinv, hA, N_NODES);
  agg_k<<<AGG_BLOCKS, 256, 0, stream>>>(hA, dinv, rp4, csr, b3, hB, sumsAll + 256);

  // pool (BN3 inline from sums) + classify
  pool_k<<<NB_POOL, 64, 0, stream>>>(hB, sumsAll + 256, g3, be3, batch, psum, pcnt);
  classify_k<<<N_GRAPHS, 256, 0, stream>>>(psum, pcnt, cg_, cm, temp, out);
}

// Round 10
// 589.113 us; speedup vs baseline: 1.1752x; 1.0198x over previous
//
#include <hip/hip_runtime.h>
#include <math.h>

#define N_NODES 100000
#define N_EDGES 3200000
#define N_GRAPHS 64
#define IN_DIM 128
#define HID 64
#define BN_EPS 1e-5f

#define PSHIFT 9
#define PBS 512
#define NPB ((N_NODES + PBS - 1) / PBS)  // 196
#define PART_BLOCKS 256
#define CHUNK_E (N_EDGES / PART_BLOCKS)  // 12500 (multiple of 4)

#define QBOUND 25000
#define AGG_BLOCKS 2048

typedef unsigned short ushort_t;

__device__ __forceinline__ float bflo(unsigned u) { return __uint_as_float(u << 16); }
__device__ __forceinline__ float bfhi(unsigned u) { return __uint_as_float(u & 0xFFFF0000u); }
__device__ __forceinline__ float bfu(ushort_t u) { return __uint_as_float((unsigned)u << 16); }
__device__ __forceinline__ unsigned f2bf(float f) {  // RNE
  unsigned u = __float_as_uint(f);
  return (u + 0x7FFFu + ((u >> 16) & 1u)) >> 16;
}

// ---------------- CSR build: two-level bucket sort, int4-vectorized ----------------

__global__ __launch_bounds__(256) void ghist_k(const int* __restrict__ ei,
                                               int* __restrict__ gh) {
  __shared__ int h[NPB];
  for (int i = threadIdx.x; i < NPB; i += 256) h[i] = 0;
  __syncthreads();
  const int4* d4 = (const int4*)(ei + N_EDGES);
  int n4 = N_EDGES / 4;
  int stride = gridDim.x * 256;
  for (int i = blockIdx.x * 256 + threadIdx.x; i < n4; i += stride) {
    int4 d = d4[i];
    atomicAdd(&h[d.x >> PSHIFT], 1);
    atomicAdd(&h[d.y >> PSHIFT], 1);
    atomicAdd(&h[d.z >> PSHIFT], 1);
    atomicAdd(&h[d.w >> PSHIFT], 1);
  }
  __syncthreads();
  for (int i = threadIdx.x; i < NPB; i += 256) {
    int v = h[i];
    if (v) atomicAdd(&gh[i], v);
  }
}

__global__ __launch_bounds__(256) void gscan_k(const int* __restrict__ gh,
                                               int* __restrict__ boff,
                                               int* __restrict__ gcur) {
  __shared__ int sa[256], sb[256];
  int t = threadIdx.x;
  int v = (t < NPB) ? gh[t] : 0;
  sa[t] = v;
  __syncthreads();
  int* src = sa; int* dst = sb;
  for (int o = 1; o < 256; o <<= 1) {
    dst[t] = src[t] + ((t >= o) ? src[t - o] : 0);
    __syncthreads();
    int* tmp = src; src = dst; dst = tmp;
  }
  if (t < NPB) {
    int excl = src[t] - v;
    boff[t] = excl;
    gcur[t] = excl;
    if (t == NPB - 1) boff[NPB] = src[t];
  }
}

__global__ __launch_bounds__(512) void part_k(const int* __restrict__ ei,
                                              int* __restrict__ gcur,
                                              unsigned* __restrict__ tmp) {
  __shared__ int lh[NPB];
  __shared__ int lcur[NPB];
  int t = threadIdx.x;
  for (int i = t; i < NPB; i += 512) lh[i] = 0;
  __syncthreads();
  int q0 = blockIdx.x * (CHUNK_E / 4);
  int q1 = q0 + CHUNK_E / 4;
  const int4* d4 = (const int4*)(ei + N_EDGES);
  const int4* s4 = (const int4*)ei;
  for (int i = q0 + t; i < q1; i += 512) {
    int4 d = d4[i];
    atomicAdd(&lh[d.x >> PSHIFT], 1);
    atomicAdd(&lh[d.y >> PSHIFT], 1);
    atomicAdd(&lh[d.z >> PSHIFT], 1);
    atomicAdd(&lh[d.w >> PSHIFT], 1);
  }
  __syncthreads();
  for (int i = t; i < NPB; i += 512) {
    int v = lh[i];
    lcur[i] = v ? atomicAdd(&gcur[i], v) : 0;
  }
  __syncthreads();
  for (int i = q0 + t; i < q1; i += 512) {
    int4 d = d4[i];
    int4 s = s4[i];
    int b0 = d.x >> PSHIFT, b1 = d.y >> PSHIFT, b2 = d.z >> PSHIFT, b3 = d.w >> PSHIFT;
    int p0 = atomicAdd(&lcur[b0], 1);
    int p1 = atomicAdd(&lcur[b1], 1);
    int p2 = atomicAdd(&lcur[b2], 1);
    int p3 = atomicAdd(&lcur[b3], 1);
    tmp[p0] = ((unsigned)(d.x & (PBS - 1)) << 17) | (unsigned)s.x;
    tmp[p1] = ((unsigned)(d.y & (PBS - 1)) << 17) | (unsigned)s.y;
    tmp[p2] = ((unsigned)(d.z & (PBS - 1)) << 17) | (unsigned)s.z;
    tmp[p3] = ((unsigned)(d.w & (PBS - 1)) << 17) | (unsigned)s.w;
  }
}

// fused per-bucket: histogram per (node, src-quartile) -> rp4/dinv -> place
__global__ __launch_bounds__(512) void bwork_k(
    const unsigned* __restrict__ tmp, const int* __restrict__ boff,
    int* __restrict__ rp4, float* __restrict__ dinv, int* __restrict__ csr) {
  int b = blockIdx.x;
  int base = boff[b], end = boff[b + 1];
  int t = threadIdx.x;
  __shared__ int cnt[PBS * 4];
  __shared__ int cur[PBS * 4];
  __shared__ int sa[PBS], sb[PBS];
  for (int i = t; i < PBS * 4; i += 512) cnt[i] = 0;
  __syncthreads();
  int a0 = (base + 3) & ~3;
  int a1 = end & ~3;
  if (a1 < a0) { a0 = end; a1 = end; }  // degenerate tiny bucket
  const uint4* t4 = (const uint4*)tmp;
#define HIST1(U) { unsigned u_ = (U); int nl_ = u_ >> 17; int s_ = u_ & 0x1FFFF; \
    int qq_ = (s_ >= QBOUND) + (s_ >= 2*QBOUND) + (s_ >= 3*QBOUND); \
    atomicAdd(&cnt[nl_ * 4 + qq_], 1); }
  if (base + t < a0) HIST1(tmp[base + t]);
  for (int i = a0 / 4 + t; i < a1 / 4; i += 512) {
    uint4 u = t4[i];
    HIST1(u.x) HIST1(u.y) HIST1(u.z) HIST1(u.w)
  }
  if (a1 + t < end) HIST1(tmp[a1 + t]);
#undef HIST1
  __syncthreads();
  int c0 = cnt[t * 4], c1 = cnt[t * 4 + 1], c2 = cnt[t * 4 + 2], c3 = cnt[t * 4 + 3];
  int tsum = c0 + c1 + c2 + c3;
  sa[t] = tsum;
  __syncthreads();
  int* src_ = sa; int* dst_ = sb;
  for (int o = 1; o < PBS; o <<= 1) {
    dst_[t] = src_[t] + ((t >= o) ? src_[t - o] : 0);
    __syncthreads();
    int* z = src_; src_ = dst_; dst_ = z;
  }
  int nb = src_[t] - tsum;  // exclusive node base within bucket
  int o0 = nb, o1 = nb + c0, o2 = nb + c0 + c1, o3 = nb + c0 + c1 + c2;
  cur[t * 4] = o0; cur[t * 4 + 1] = o1; cur[t * 4 + 2] = o2; cur[t * 4 + 3] = o3;
  int n = b * PBS + t;
  if (n < N_NODES) {
    rp4[4 * n] = base + o0;
    rp4[4 * n + 1] = base + o1;
    rp4[4 * n + 2] = base + o2;
    rp4[4 * n + 3] = base + o3;
    dinv[n] = rsqrtf((float)(tsum + 1));  // +1 self loop
    if (n == N_NODES - 1) rp4[4 * N_NODES] = base + nb + tsum;
  }
  __syncthreads();
#define PLACE1(U) { unsigned u_ = (U); int nl_ = u_ >> 17; int s_ = u_ & 0x1FFFF; \
    int qq_ = (s_ >= QBOUND) + (s_ >= 2*QBOUND) + (s_ >= 3*QBOUND); \
    int p_ = atomicAdd(&cur[nl_ * 4 + qq_], 1); \
    csr[base + p_] = s_ << 7; }
  if (base + t < a0) PLACE1(tmp[base + t]);
  for (int i = a0 / 4 + t; i < a1 / 4; i += 512) {
    uint4 u = t4[i];
    PLACE1(u.x) PLACE1(u.y) PLACE1(u.z) PLACE1(u.w)
  }
  if (a1 + t < end) PLACE1(tmp[a1 + t]);
#undef PLACE1
}

// ---------------- GEMM: hs[n][c] = dinv[n] * (BN(X)[n] @ W)[c] -> bf16 ----------------
// XBF16: input rows are bf16 (128 B/row). APPLY computes BN inline from sums.

template <int K, bool XBF16, bool APPLY, bool RELU>
__global__ __launch_bounds__(256) void gemm_k(
    const void* __restrict__ Xv, const float* __restrict__ W,
    const float* __restrict__ sums, const float* __restrict__ gamma,
    const float* __restrict__ beta,
    const float* __restrict__ dinv, ushort_t* __restrict__ out, int nrows) {
  constexpr int WROW = K + 1;
  __shared__ float wt[64 * WROW];   // wt[c][k]  (W transposed)
  __shared__ float xs[64 * 68];     // xs[r][k]
  const int tid = threadIdx.x;
  const int tc = tid & 15;
  const int tr = tid >> 4;

  float sc4[4], sh4[4];
  if (APPLY) {
    const int kq = tid & 15;
#pragma unroll
    for (int t = 0; t < 4; ++t) {
      int kg = kq * 4 + t;
      float m = sums[kg] / (float)N_NODES;
      float v = sums[64 + kg] / (float)N_NODES - m * m;
      float s = gamma[kg] * rsqrtf(v + BN_EPS);
      sc4[t] = s;
      sh4[t] = beta[kg] - m * s;
    }
  }

  for (int idx = tid; idx < K * 64; idx += 256) {
    int k = idx >> 6, c = idx & 63;
    wt[c * WROW + k] = W[idx];
  }

  const int rowbase = blockIdx.x * 64;
  float acc[4][4] = {};

  for (int kc = 0; kc < K; kc += 64) {
    __syncthreads();
    {
      const int kq = tid & 15;
      const int rr = tid >> 4;
#pragma unroll
      for (int p = 0; p < 4; ++p) {
        int r = rr + p * 16;
        int grow = rowbase + r;
        float4 v = make_float4(0.f, 0.f, 0.f, 0.f);
        if (grow < nrows) {
          if (XBF16) {
            uint2 uv = *(const uint2*)((const char*)Xv + (size_t)grow * 128 + kq * 8);
            v = make_float4(bflo(uv.x), bfhi(uv.x), bflo(uv.y), bfhi(uv.y));
          } else {
            v = *(const float4*)((const float*)Xv + (size_t)grow * K + kc + kq * 4);
          }
        }
        if (APPLY) {
          v.x = v.x * sc4[0] + sh4[0];
          v.y = v.y * sc4[1] + sh4[1];
          v.z = v.z * sc4[2] + sh4[2];
          v.w = v.w * sc4[3] + sh4[3];
          if (RELU) {
            v.x = fmaxf(v.x, 0.f); v.y = fmaxf(v.y, 0.f);
            v.z = fmaxf(v.z, 0.f); v.w = fmaxf(v.w, 0.f);
          }
        }
        *(float4*)(xs + r * 68 + kq * 4) = v;
      }
    }
    __syncthreads();
#pragma unroll 4
    for (int k0 = 0; k0 < 64; k0 += 4) {
      float4 xv[4], wv[4];
#pragma unroll
      for (int i = 0; i < 4; ++i)
        xv[i] = *(const float4*)(xs + (tr * 4 + i) * 68 + k0);
#pragma unroll
      for (int j = 0; j < 4; ++j)
        wv[j] = *(const float4*)(wt + (4 * tc + j) * WROW + kc + k0);
#pragma unroll
      for (int i = 0; i < 4; ++i)
#pragma unroll
        for (int j = 0; j < 4; ++j)
          acc[i][j] += xv[i].x * wv[j].x + xv[i].y * wv[j].y +
                       xv[i].z * wv[j].z + xv[i].w * wv[j].w;
    }
  }

  char* ob = (char*)out;
#pragma unroll
  for (int i = 0; i < 4; ++i) {
    int grow = rowbase + tr * 4 + i;
    if (grow < nrows) {
      float dn = dinv[grow];
      uint2 o;
      o.x = f2bf(acc[i][0] * dn) | (f2bf(acc[i][1] * dn) << 16);
      o.y = f2bf(acc[i][2] * dn) | (f2bf(acc[i][3] * dn) << 16);
      *(uint2*)(ob + (size_t)grow * 128 + tc * 8) = o;
    }
  }
}

// ---------------- aggregation (x8 MLP) -> bf16 out + fused BN stats ----------------

__global__ __launch_bounds__(256) void agg_k(
    const ushort_t* __restrict__ hs, const float* __restrict__ dinv,
    const int* __restrict__ rp4, const int* __restrict__ csr,
    const float* __restrict__ bias, ushort_t* __restrict__ out,
    float* __restrict__ sums) {
  const int tid = threadIdx.x;
  const int w = tid >> 6;
  const int lane = tid & 63;
  const int g = lane >> 4;     // node slot 0..3
  const int q = lane & 15;     // feature quad
  const char* hb = (const char*)hs;
  char* ob = (char*)out;

  float4 bval = *(const float4*)(bias + q * 4);
  float4 s = make_float4(0.f, 0.f, 0.f, 0.f);
  float4 s2 = make_float4(0.f, 0.f, 0.f, 0.f);

  for (int n = blockIdx.x * 16 + w * 4 + g; n < N_NODES; n += AGG_BLOCKS * 16) {
    int r0 = rp4[4 * n];
    int cnt = rp4[4 * n + 4] - r0;
    float4 aA = {0, 0, 0, 0}, aB = {0, 0, 0, 0};
    int j = 0;
    for (; j + 8 <= cnt; j += 8) {
      int e0 = csr[r0 + j + 0], e1 = csr[r0 + j + 1];
      int e2 = csr[r0 + j + 2], e3 = csr[r0 + j + 3];
      int e4 = csr[r0 + j + 4], e5 = csr[r0 + j + 5];
      int e6 = csr[r0 + j + 6], e7 = csr[r0 + j + 7];
      uint2 v0 = *(const uint2*)(hb + (size_t)(unsigned)e0 + (q << 3));
      uint2 v1 = *(const uint2*)(hb + (size_t)(unsigned)e1 + (q << 3));
      uint2 v2 = *(const uint2*)(hb + (size_t)(unsigned)e2 + (q << 3));
      uint2 v3 = *(const uint2*)(hb + (size_t)(unsigned)e3 + (q << 3));
      uint2 v4 = *(const uint2*)(hb + (size_t)(unsigned)e4 + (q << 3));
      uint2 v5 = *(const uint2*)(hb + (size_t)(unsigned)e5 + (q << 3));
      uint2 v6 = *(const uint2*)(hb + (size_t)(unsigned)e6 + (q << 3));
      uint2 v7 = *(const uint2*)(hb + (size_t)(unsigned)e7 + (q << 3));
      aA.x += bflo(v0.x); aA.y += bfhi(v0.x); aA.z += bflo(v0.y); aA.w += bfhi(v0.y);
      aB.x += bflo(v1.x); aB.y += bfhi(v1.x); aB.z += bflo(v1.y); aB.w += bfhi(v1.y);
      aA.x += bflo(v2.x); aA.y += bfhi(v2.x); aA.z += bflo(v2.y); aA.w += bfhi(v2.y);
      aB.x += bflo(v3.x); aB.y += bfhi(v3.x); aB.z += bflo(v3.y); aB.w += bfhi(v3.y);
      aA.x += bflo(v4.x); aA.y += bfhi(v4.x); aA.z += bflo(v4.y); aA.w += bfhi(v4.y);
      aB.x += bflo(v5.x); aB.y += bfhi(v5.x); aB.z += bflo(v5.y); aB.w += bfhi(v5.y);
      aA.x += bflo(v6.x); aA.y += bfhi(v6.x); aA.z += bflo(v6.y); aA.w += bfhi(v6.y);
      aB.x += bflo(v7.x); aB.y += bfhi(v7.x); aB.z += bflo(v7.y); aB.w += bfhi(v7.y);
    }
    for (; j + 2 <= cnt; j += 2) {
      int e0 = csr[r0 + j + 0], e1 = csr[r0 + j + 1];
      uint2 v0 = *(const uint2*)(hb + (size_t)(unsigned)e0 + (q << 3));
      uint2 v1 = *(const uint2*)(hb + (size_t)(unsigned)e1 + (q << 3));
      aA.x += bflo(v0.x); aA.y += bfhi(v0.x); aA.z += bflo(v0.y); aA.w += bfhi(v0.y);
      aB.x += bflo(v1.x); aB.y += bfhi(v1.x); aB.z += bflo(v1.y); aB.w += bfhi(v1.y);
    }
    if (j < cnt) {
      int e0 = csr[r0 + j];
      uint2 v0 = *(const uint2*)(hb + (size_t)(unsigned)e0 + (q << 3));
      aA.x += bflo(v0.x); aA.y += bfhi(v0.x); aA.z += bflo(v0.y); aA.w += bfhi(v0.y);
    }
    // self row + finalize
    uint2 u = *(const uint2*)(hb + ((size_t)n << 7) + (q << 3));
    float4 a;
    a.x = aA.x + aB.x + bflo(u.x);
    a.y = aA.y + aB.y + bfhi(u.x);
    a.z = aA.z + aB.z + bflo(u.y);
    a.w = aA.w + aB.w + bfhi(u.y);
    float dn = dinv[n];
    a.x = a.x * dn + bval.x; a.y = a.y * dn + bval.y;
    a.z = a.z * dn + bval.z; a.w = a.w * dn + bval.w;
    uint2 o;
    o.x = f2bf(a.x) | (f2bf(a.y) << 16);
    o.y = f2bf(a.z) | (f2bf(a.w) << 16);
    *(uint2*)(ob + ((size_t)n << 7) + (q << 3)) = o;
    s.x += a.x; s.y += a.y; s.z += a.z; s.w += a.w;
    s2.x += a.x * a.x; s2.y += a.y * a.y;
    s2.z += a.z * a.z; s2.w += a.w * a.w;
  }

  __shared__ float rs[16][64];
  __shared__ float rs2[16][64];
  *(float4*)(&rs[w * 4 + g][q * 4]) = s;
  *(float4*)(&rs2[w * 4 + g][q * 4]) = s2;
  __syncthreads();
  int c = tid & 63;
  int r0_ = tid >> 6;
  float a = rs[r0_][c] + rs[r0_ + 4][c] + rs[r0_ + 8][c] + rs[r0_ + 12][c];
  float a2 = rs2[r0_][c] + rs2[r0_ + 4][c] + rs2[r0_ + 8][c] + rs2[r0_ + 12][c];
  __syncthreads();
  rs[r0_][c] = a;
  rs2[r0_][c] = a2;
  __syncthreads();
  if (r0_ == 0) {
    atomicAdd(&sums[c], rs[0][c] + rs[1][c] + rs[2][c] + rs[3][c]);
    atomicAdd(&sums[64 + c], rs2[0][c] + rs2[1][c] + rs2[2][c] + rs2[3][c]);
  }
}

// ---------------- pooling (batch sorted); BN3 inline; bf16 input ----------------

#define POOL_CHUNK 32
__global__ __launch_bounds__(256) void pool_k(
    const ushort_t* __restrict__ h, const float* __restrict__ sums,
    const float* __restrict__ gamma, const float* __restrict__ beta,
    const int* __restrict__ batch,
    float* __restrict__ psum, float* __restrict__ pcnt) {
  int w = threadIdx.x >> 6;
  int lane = threadIdx.x & 63;
  int start = (blockIdx.x * 4 + w) * POOL_CHUNK;
  if (start >= N_NODES) return;
  int end = min(start + POOL_CHUNK, N_NODES);
  float m = sums[lane] / (float)N_NODES;
  float v = sums[64 + lane] / (float)N_NODES - m * m;
  float sc = gamma[lane] * rsqrtf(v + BN_EPS);
  float sh = beta[lane] - m * sc;
  float acc = 0.f, cnt = 0.f;
  int cur = batch[start];
  for (int n = start; n < end; ++n) {
    int g = batch[n];
    if (g != cur) {
      atomicAdd(&psum[cur * 64 + lane], acc);
      if (lane == 0) atomicAdd(&pcnt[cur], cnt);
      acc = 0.f; cnt = 0.f; cur = g;
    }
    acc += bfu(h[(size_t)n * 64 + lane]) * sc + sh;
    cnt += 1.f;
  }
  atomicAdd(&psum[cur * 64 + lane], acc);
  if (lane == 0) atomicAdd(&pcnt[cur], cnt);
}

// ---------------- centroid classifier ----------------

__global__ void classify_k(const float* __restrict__ psum, const float* __restrict__ pcnt,
                           const float* __restrict__ cg_, const float* __restrict__ cm,
                           const float* __restrict__ temp, float* __restrict__ out) {
  int g = blockIdx.x;
  int t = threadIdx.x;
  __shared__ float emb[64];
  __shared__ float dist[208];
  if (t < 64) emb[t] = psum[g * 64 + t] / fmaxf(pcnt[g], 1.0f);
  __syncthreads();
  if (t < 197) {
    const float* C = (t < 5) ? (cg_ + t * 64) : (cm + (t - 5) * 64);
    float d = 0.f;
#pragma unroll 8
    for (int k = 0; k < 64; ++k) {
      float df = emb[k] - C[k];
      d += df * df;
    }
    dist[t] = d;
  }
  __syncthreads();
  float tv = temp[0];
  if (t == 64) {
    float m = dist[0];
    for (int j = 1; j < 5; ++j) m = fminf(m, dist[j]);
    out[g * 65] = -m / tv;
  }
  if (t < 64) {
    float m = fminf(dist[5 + t * 3], fminf(dist[5 + t * 3 + 1], dist[5 + t * 3 + 2]));
    out[g * 65 + 1 + t] = -m / tv;
  }
}

// ---------------- launch ----------------

extern "C" void kernel_launch(void* const* d_in, const int* in_sizes, int n_in,
                              void* d_out, int out_size, void* d_ws, size_t ws_size,
                              hipStream_t stream) {
  const float* x   = (const float*)d_in[0];
  const int* ei    = (const int*)d_in[1];
  const int* batch = (const int*)d_in[2];
  const float* W1 = (const float*)d_in[3];  const float* b1 = (const float*)d_in[4];
  const float* g1 = (const float*)d_in[5];  const float* be1 = (const float*)d_in[6];
  const float* W2 = (const float*)d_in[7];  const float* b2 = (const float*)d_in[8];
  const float* g2 = (const float*)d_in[9];  const float* be2 = (const float*)d_in[10];
  const float* W3 = (const float*)d_in[11]; const float* b3 = (const float*)d_in[12];
  const float* g3 = (const float*)d_in[13]; const float* be3 = (const float*)d_in[14];
  const float* cg_ = (const float*)d_in[15];
  const float* cm = (const float*)d_in[16];
  const float* temp = (const float*)d_in[17];
  float* out = (float*)d_out;

  char* ws = (char*)d_ws;
  size_t off = 0;
  auto alloc = [&](size_t bytes) -> void* {
    void* p = ws + off;
    off = (off + bytes + 255) & ~(size_t)255;
    return p;
  };
  int* gh        = (int*)alloc((size_t)NPB * 4);
  int* boff      = (int*)alloc((size_t)(NPB + 1) * 4);
  int* gcur      = (int*)alloc((size_t)NPB * 4);
  unsigned* tmp  = (unsigned*)alloc((size_t)N_EDGES * 4);
  int* csr       = (int*)alloc((size_t)N_EDGES * 4);
  int* rp4       = (int*)alloc((size_t)(4 * N_NODES + 1) * 4);
  float* dinv    = (float*)alloc((size_t)N_NODES * 4);
  ushort_t* hA   = (ushort_t*)alloc((size_t)N_NODES * 64 * 2);  // bf16 hs
  ushort_t* hB   = (ushort_t*)alloc((size_t)N_NODES * 64 * 2);  // bf16 h (pre-BN)
  float* sumsAll = (float*)alloc(3 * 128 * 4);
  float* psum    = (float*)alloc(64 * 64 * 4);
  float* pcnt    = (float*)alloc(64 * 4);

  hipMemsetAsync(gh, 0, (size_t)NPB * 4, stream);
  hipMemsetAsync(sumsAll, 0, 3 * 128 * 4, stream);
  hipMemsetAsync(psum, 0, 64 * 64 * 4, stream);
  hipMemsetAsync(pcnt, 0, 64 * 4, stream);

  const int NB_GEMM = (N_NODES + 63) / 64;   // 1563
  const int NB_POOL = (N_NODES + POOL_CHUNK * 4 - 1) / (POOL_CHUNK * 4);  // 782

  // CSR build
  ghist_k<<<512, 256, 0, stream>>>(ei, gh);
  gscan_k<<<1, 256, 0, stream>>>(gh, boff, gcur);
  part_k<<<PART_BLOCKS, 512, 0, stream>>>(ei, gcur, tmp);
  bwork_k<<<NPB, 512, 0, stream>>>(tmp, boff, rp4, dinv, csr);

  // layer 1
  gemm_k<IN_DIM, false, false, false><<<NB_GEMM, 256, 0, stream>>>(x, W1, nullptr, nullptr, nullptr, dinv, hA, N_NODES);
  agg_k<<<AGG_BLOCKS, 256, 0, stream>>>(hA, dinv, rp4, csr, b1, hB, sumsAll);

  // layer 2 (BN1+ReLU inline from sums, bf16 input)
  gemm_k<HID, true, true, true><<<NB_GEMM, 256, 0, stream>>>(hB, W2, sumsAll, g1, be1, dinv, hA, N_NODES);
  agg_k<<<AGG_BLOCKS, 256, 0, stream>>>(hA, dinv, rp4, csr, b2, hB, sumsAll + 128);

  // layer 3 (BN2+ReLU inline from sums, bf16 input)
  gemm_k<HID, true, true, true><<<NB_GEMM, 256, 0, stream>>>(hB, W3, sumsAll + 128, g2, be2, dinv, hA, N_NODES);
  agg_k<<<AGG_BLOCKS, 256, 0, stream>>>(hA, dinv, rp4, csr, b3, hB, sumsAll + 256);

  // pool (BN3 inline from sums) + classify
  pool_k<<<NB_POOL, 256, 0, stream>>>(hB, sumsAll + 256, g3, be3, batch, psum, pcnt);
  classify_k<<<N_GRAPHS, 256, 0, stream>>>(psum, pcnt, cg_, cm, temp, out);
}

// Round 11
// 565.735 us; speedup vs baseline: 1.2237x; 1.0413x over previous
//
#include <hip/hip_runtime.h>
#include <math.h>

#define N_NODES 100000
#define N_EDGES 3200000
#define N_GRAPHS 64
#define IN_DIM 128
#define HID 64
#define BN_EPS 1e-5f

#define PSHIFT 9
#define PBS 512
#define NPB ((N_NODES + PBS - 1) / PBS)  // 196
#define PART_BLOCKS 256
#define CHUNK_E (N_EDGES / PART_BLOCKS)  // 12500 (multiple of 4)

#define QBOUND 25000
#define AGG_BLOCKS 2048

typedef unsigned short ushort_t;
typedef __attribute__((ext_vector_type(8))) short bf16x8;
typedef __attribute__((ext_vector_type(4))) float f32x4;

__device__ __forceinline__ float bflo(unsigned u) { return __uint_as_float(u << 16); }
__device__ __forceinline__ float bfhi(unsigned u) { return __uint_as_float(u & 0xFFFF0000u); }
__device__ __forceinline__ float bfu(ushort_t u) { return __uint_as_float((unsigned)u << 16); }
__device__ __forceinline__ unsigned f2bf(float f) {  // RNE
  unsigned u = __float_as_uint(f);
  return (u + 0x7FFFu + ((u >> 16) & 1u)) >> 16;
}

// ---------------- CSR build: two-level bucket sort, int4-vectorized ----------------

__global__ __launch_bounds__(256) void ghist_k(const int* __restrict__ ei,
                                               int* __restrict__ gh) {
  __shared__ int h[NPB];
  for (int i = threadIdx.x; i < NPB; i += 256) h[i] = 0;
  __syncthreads();
  const int4* d4 = (const int4*)(ei + N_EDGES);
  int n4 = N_EDGES / 4;
  int stride = gridDim.x * 256;
  for (int i = blockIdx.x * 256 + threadIdx.x; i < n4; i += stride) {
    int4 d = d4[i];
    atomicAdd(&h[d.x >> PSHIFT], 1);
    atomicAdd(&h[d.y >> PSHIFT], 1);
    atomicAdd(&h[d.z >> PSHIFT], 1);
    atomicAdd(&h[d.w >> PSHIFT], 1);
  }
  __syncthreads();
  for (int i = threadIdx.x; i < NPB; i += 256) {
    int v = h[i];
    if (v) atomicAdd(&gh[i], v);
  }
}

__global__ __launch_bounds__(256) void gscan_k(const int* __restrict__ gh,
                                               int* __restrict__ boff,
                                               int* __restrict__ gcur) {
  __shared__ int sa[256], sb[256];
  int t = threadIdx.x;
  int v = (t < NPB) ? gh[t] : 0;
  sa[t] = v;
  __syncthreads();
  int* src = sa; int* dst = sb;
  for (int o = 1; o < 256; o <<= 1) {
    dst[t] = src[t] + ((t >= o) ? src[t - o] : 0);
    __syncthreads();
    int* tmp = src; src = dst; dst = tmp;
  }
  if (t < NPB) {
    int excl = src[t] - v;
    boff[t] = excl;
    gcur[t] = excl;
    if (t == NPB - 1) boff[NPB] = src[t];
  }
}

__global__ __launch_bounds__(512) void part_k(const int* __restrict__ ei,
                                              int* __restrict__ gcur,
                                              unsigned* __restrict__ tmp) {
  __shared__ int lh[NPB];
  __shared__ int lcur[NPB];
  int t = threadIdx.x;
  for (int i = t; i < NPB; i += 512) lh[i] = 0;
  __syncthreads();
  int q0 = blockIdx.x * (CHUNK_E / 4);
  int q1 = q0 + CHUNK_E / 4;
  const int4* d4 = (const int4*)(ei + N_EDGES);
  const int4* s4 = (const int4*)ei;
  for (int i = q0 + t; i < q1; i += 512) {
    int4 d = d4[i];
    atomicAdd(&lh[d.x >> PSHIFT], 1);
    atomicAdd(&lh[d.y >> PSHIFT], 1);
    atomicAdd(&lh[d.z >> PSHIFT], 1);
    atomicAdd(&lh[d.w >> PSHIFT], 1);
  }
  __syncthreads();
  for (int i = t; i < NPB; i += 512) {
    int v = lh[i];
    lcur[i] = v ? atomicAdd(&gcur[i], v) : 0;
  }
  __syncthreads();
  for (int i = q0 + t; i < q1; i += 512) {
    int4 d = d4[i];
    int4 s = s4[i];
    int b0 = d.x >> PSHIFT, b1 = d.y >> PSHIFT, b2 = d.z >> PSHIFT, b3 = d.w >> PSHIFT;
    int p0 = atomicAdd(&lcur[b0], 1);
    int p1 = atomicAdd(&lcur[b1], 1);
    int p2 = atomicAdd(&lcur[b2], 1);
    int p3 = atomicAdd(&lcur[b3], 1);
    tmp[p0] = ((unsigned)(d.x & (PBS - 1)) << 17) | (unsigned)s.x;
    tmp[p1] = ((unsigned)(d.y & (PBS - 1)) << 17) | (unsigned)s.y;
    tmp[p2] = ((unsigned)(d.z & (PBS - 1)) << 17) | (unsigned)s.z;
    tmp[p3] = ((unsigned)(d.w & (PBS - 1)) << 17) | (unsigned)s.w;
  }
}

// fused per-bucket: histogram per (node, src-quartile) -> rp4/dinv -> place
__global__ __launch_bounds__(512) void bwork_k(
    const unsigned* __restrict__ tmp, const int* __restrict__ boff,
    int* __restrict__ rp4, float* __restrict__ dinv, int* __restrict__ csr) {
  int b = blockIdx.x;
  int base = boff[b], end = boff[b + 1];
  int t = threadIdx.x;
  __shared__ int cnt[PBS * 4];
  __shared__ int cur[PBS * 4];
  __shared__ int sa[PBS], sb[PBS];
  for (int i = t; i < PBS * 4; i += 512) cnt[i] = 0;
  __syncthreads();
  int a0 = (base + 3) & ~3;
  int a1 = end & ~3;
  if (a1 < a0) { a0 = end; a1 = end; }
  const uint4* t4 = (const uint4*)tmp;
#define HIST1(U) { unsigned u_ = (U); int nl_ = u_ >> 17; int s_ = u_ & 0x1FFFF; \
    int qq_ = (s_ >= QBOUND) + (s_ >= 2*QBOUND) + (s_ >= 3*QBOUND); \
    atomicAdd(&cnt[nl_ * 4 + qq_], 1); }
  if (base + t < a0) HIST1(tmp[base + t]);
  for (int i = a0 / 4 + t; i < a1 / 4; i += 512) {
    uint4 u = t4[i];
    HIST1(u.x) HIST1(u.y) HIST1(u.z) HIST1(u.w)
  }
  if (a1 + t < end) HIST1(tmp[a1 + t]);
#undef HIST1
  __syncthreads();
  int c0 = cnt[t * 4], c1 = cnt[t * 4 + 1], c2 = cnt[t * 4 + 2], c3 = cnt[t * 4 + 3];
  int tsum = c0 + c1 + c2 + c3;
  sa[t] = tsum;
  __syncthreads();
  int* src_ = sa; int* dst_ = sb;
  for (int o = 1; o < PBS; o <<= 1) {
    dst_[t] = src_[t] + ((t >= o) ? src_[t - o] : 0);
    __syncthreads();
    int* z = src_; src_ = dst_; dst_ = z;
  }
  int nb = src_[t] - tsum;
  int o0 = nb, o1 = nb + c0, o2 = nb + c0 + c1, o3 = nb + c0 + c1 + c2;
  cur[t * 4] = o0; cur[t * 4 + 1] = o1; cur[t * 4 + 2] = o2; cur[t * 4 + 3] = o3;
  int n = b * PBS + t;
  if (n < N_NODES) {
    rp4[4 * n] = base + o0;
    rp4[4 * n + 1] = base + o1;
    rp4[4 * n + 2] = base + o2;
    rp4[4 * n + 3] = base + o3;
    dinv[n] = rsqrtf((float)(tsum + 1));  // +1 self loop
    if (n == N_NODES - 1) rp4[4 * N_NODES] = base + nb + tsum;
  }
  __syncthreads();
#define PLACE1(U) { unsigned u_ = (U); int nl_ = u_ >> 17; int s_ = u_ & 0x1FFFF; \
    int qq_ = (s_ >= QBOUND) + (s_ >= 2*QBOUND) + (s_ >= 3*QBOUND); \
    int p_ = atomicAdd(&cur[nl_ * 4 + qq_], 1); \
    csr[base + p_] = s_ << 7; }
  if (base + t < a0) PLACE1(tmp[base + t]);
  for (int i = a0 / 4 + t; i < a1 / 4; i += 512) {
    uint4 u = t4[i];
    PLACE1(u.x) PLACE1(u.y) PLACE1(u.z) PLACE1(u.w)
  }
  if (a1 + t < end) PLACE1(tmp[a1 + t]);
#undef PLACE1
}

// ---------------- MFMA GEMM: hs[n][c] = dinv[n] * (BN(X)[n] @ W)[c] -> bf16 ----------------
// Per wave: 16-row m-tile x four 16-col n-tiles via mfma_f32_16x16x32_bf16.
// A-frag loaded directly from global (lane m=lane&15, k=(lane>>4)*8+j).
// W^T staged as bf16 in LDS. D repacked via padded LDS for coalesced stores.

template <int K, bool XBF16, bool APPLY, bool RELU>
__global__ __launch_bounds__(256) void gemm_k(
    const void* __restrict__ Xv, const float* __restrict__ W,
    const float* __restrict__ sums, const float* __restrict__ gamma,
    const float* __restrict__ beta, const float* __restrict__ dinv,
    ushort_t* __restrict__ out, int nrows) {
  __shared__ ushort_t wt[64 * K];   // wt[n][k] bf16
  __shared__ float scs[128], shs[128];
  __shared__ float redo[64 * 65];   // D repack, padded
  const int tid = threadIdx.x;
  const int wv = tid >> 6;
  const int lane = tid & 63;
  const int lm = lane & 15;
  const int lq = lane >> 4;

  for (int idx = tid; idx < K * 64; idx += 256) {
    int k = idx >> 6, c = idx & 63;      // W[k][c]
    wt[c * K + k] = (ushort_t)f2bf(W[idx]);
  }
  if (APPLY) {
    for (int k = tid; k < K; k += 256) {
      float m = sums[k] / (float)N_NODES;
      float v = sums[64 + k] / (float)N_NODES - m * m;
      float s = gamma[k] * rsqrtf(v + BN_EPS);
      scs[k] = s;
      shs[k] = beta[k] - m * s;
    }
  }
  __syncthreads();

  const int rowbase = blockIdx.x * 64;
  const int grow = rowbase + wv * 16 + lm;
  const bool valid = grow < nrows;
  f32x4 acc0 = {0.f, 0.f, 0.f, 0.f};
  f32x4 acc1 = acc0, acc2 = acc0, acc3 = acc0;

#pragma unroll
  for (int k0 = 0; k0 < K; k0 += 32) {
    int kbase = k0 + lq * 8;
    bf16x8 a = {0, 0, 0, 0, 0, 0, 0, 0};
    if (valid) {
      if (XBF16) {
        uint4 u = *(const uint4*)((const char*)Xv + ((size_t)grow * 64 + kbase) * 2);
        if (APPLY) {
          float4 sc0 = *(const float4*)&scs[kbase];
          float4 sc1 = *(const float4*)&scs[kbase + 4];
          float4 sh0 = *(const float4*)&shs[kbase];
          float4 sh1 = *(const float4*)&shs[kbase + 4];
          float f0 = bflo(u.x) * sc0.x + sh0.x, f1 = bfhi(u.x) * sc0.y + sh0.y;
          float f2 = bflo(u.y) * sc0.z + sh0.z, f3 = bfhi(u.y) * sc0.w + sh0.w;
          float f4 = bflo(u.z) * sc1.x + sh1.x, f5 = bfhi(u.z) * sc1.y + sh1.y;
          float f6 = bflo(u.w) * sc1.z + sh1.z, f7 = bfhi(u.w) * sc1.w + sh1.w;
          if (RELU) {
            f0 = fmaxf(f0, 0.f); f1 = fmaxf(f1, 0.f);
            f2 = fmaxf(f2, 0.f); f3 = fmaxf(f3, 0.f);
            f4 = fmaxf(f4, 0.f); f5 = fmaxf(f5, 0.f);
            f6 = fmaxf(f6, 0.f); f7 = fmaxf(f7, 0.f);
          }
          a[0] = (short)f2bf(f0); a[1] = (short)f2bf(f1);
          a[2] = (short)f2bf(f2); a[3] = (short)f2bf(f3);
          a[4] = (short)f2bf(f4); a[5] = (short)f2bf(f5);
          a[6] = (short)f2bf(f6); a[7] = (short)f2bf(f7);
        } else {
          a = *(const bf16x8*)&u;
        }
      } else {
        const float* xp = (const float*)Xv + (size_t)grow * K + kbase;
        float4 xa = *(const float4*)xp;
        float4 xb = *(const float4*)(xp + 4);
        a[0] = (short)f2bf(xa.x); a[1] = (short)f2bf(xa.y);
        a[2] = (short)f2bf(xa.z); a[3] = (short)f2bf(xa.w);
        a[4] = (short)f2bf(xb.x); a[5] = (short)f2bf(xb.y);
        a[6] = (short)f2bf(xb.z); a[7] = (short)f2bf(xb.w);
      }
    }
    bf16x8 b0 = *(const bf16x8*)(wt + (0 + lm) * K + kbase);
    bf16x8 b1 = *(const bf16x8*)(wt + (16 + lm) * K + kbase);
    bf16x8 b2 = *(const bf16x8*)(wt + (32 + lm) * K + kbase);
    bf16x8 b3 = *(const bf16x8*)(wt + (48 + lm) * K + kbase);
    acc0 = __builtin_amdgcn_mfma_f32_16x16x32_bf16(a, b0, acc0, 0, 0, 0);
    acc1 = __builtin_amdgcn_mfma_f32_16x16x32_bf16(a, b1, acc1, 0, 0, 0);
    acc2 = __builtin_amdgcn_mfma_f32_16x16x32_bf16(a, b2, acc2, 0, 0, 0);
    acc3 = __builtin_amdgcn_mfma_f32_16x16x32_bf16(a, b3, acc3, 0, 0, 0);
  }

  // D layout: row = (lane>>4)*4 + reg, col = lane&15  -> repack via LDS
#pragma unroll
  for (int r = 0; r < 4; ++r) {
    int rr = wv * 16 + lq * 4 + r;
    redo[rr * 65 + lm] = acc0[r];
    redo[rr * 65 + 16 + lm] = acc1[r];
    redo[rr * 65 + 32 + lm] = acc2[r];
    redo[rr * 65 + 48 + lm] = acc3[r];
  }
  __syncthreads();
  {
    int r = tid >> 2;
    int cq = (tid & 3) * 16;
    int gr = rowbase + r;
    if (gr < nrows) {
      float dn = dinv[gr];
      const float* sp = &redo[r * 65 + cq];
      unsigned p[8];
#pragma unroll
      for (int i = 0; i < 8; ++i)
        p[i] = f2bf(sp[2 * i] * dn) | (f2bf(sp[2 * i + 1] * dn) << 16);
      char* ob = (char*)out + ((size_t)gr * 64 + cq) * 2;
      *(uint4*)ob = make_uint4(p[0], p[1], p[2], p[3]);
      *(uint4*)(ob + 16) = make_uint4(p[4], p[5], p[6], p[7]);
    }
  }
}

// ---------------- aggregation (x8 MLP) -> bf16 out + fused BN stats ----------------

__global__ __launch_bounds__(256) void agg_k(
    const ushort_t* __restrict__ hs, const float* __restrict__ dinv,
    const int* __restrict__ rp4, const int* __restrict__ csr,
    const float* __restrict__ bias, ushort_t* __restrict__ out,
    float* __restrict__ sums) {
  const int tid = threadIdx.x;
  const int w = tid >> 6;
  const int lane = tid & 63;
  const int g = lane >> 4;     // node slot 0..3
  const int q = lane & 15;     // feature quad
  const char* hb = (const char*)hs;
  char* ob = (char*)out;

  float4 bval = *(const float4*)(bias + q * 4);
  float4 s = make_float4(0.f, 0.f, 0.f, 0.f);
  float4 s2 = make_float4(0.f, 0.f, 0.f, 0.f);

  for (int n = blockIdx.x * 16 + w * 4 + g; n < N_NODES; n += AGG_BLOCKS * 16) {
    int r0 = rp4[4 * n];
    int cnt = rp4[4 * n + 4] - r0;
    float4 aA = {0, 0, 0, 0}, aB = {0, 0, 0, 0};
    int j = 0;
    for (; j + 8 <= cnt; j += 8) {
      int e0 = csr[r0 + j + 0], e1 = csr[r0 + j + 1];
      int e2 = csr[r0 + j + 2], e3 = csr[r0 + j + 3];
      int e4 = csr[r0 + j + 4], e5 = csr[r0 + j + 5];
      int e6 = csr[r0 + j + 6], e7 = csr[r0 + j + 7];
      uint2 v0 = *(const uint2*)(hb + (size_t)(unsigned)e0 + (q << 3));
      uint2 v1 = *(const uint2*)(hb + (size_t)(unsigned)e1 + (q << 3));
      uint2 v2 = *(const uint2*)(hb + (size_t)(unsigned)e2 + (q << 3));
      uint2 v3 = *(const uint2*)(hb + (size_t)(unsigned)e3 + (q << 3));
      uint2 v4 = *(const uint2*)(hb + (size_t)(unsigned)e4 + (q << 3));
      uint2 v5 = *(const uint2*)(hb + (size_t)(unsigned)e5 + (q << 3));
      uint2 v6 = *(const uint2*)(hb + (size_t)(unsigned)e6 + (q << 3));
      uint2 v7 = *(const uint2*)(hb + (size_t)(unsigned)e7 + (q << 3));
      aA.x += bflo(v0.x); aA.y += bfhi(v0.x); aA.z += bflo(v0.y); aA.w += bfhi(v0.y);
      aB.x += bflo(v1.x); aB.y += bfhi(v1.x); aB.z += bflo(v1.y); aB.w += bfhi(v1.y);
      aA.x += bflo(v2.x); aA.y += bfhi(v2.x); aA.z += bflo(v2.y); aA.w += bfhi(v2.y);
      aB.x += bflo(v3.x); aB.y += bfhi(v3.x); aB.z += bflo(v3.y); aB.w += bfhi(v3.y);
      aA.x += bflo(v4.x); aA.y += bfhi(v4.x); aA.z += bflo(v4.y); aA.w += bfhi(v4.y);
      aB.x += bflo(v5.x); aB.y += bfhi(v5.x); aB.z += bflo(v5.y); aB.w += bfhi(v5.y);
      aA.x += bflo(v6.x); aA.y += bfhi(v6.x); aA.z += bflo(v6.y); aA.w += bfhi(v6.y);
      aB.x += bflo(v7.x); aB.y += bfhi(v7.x); aB.z += bflo(v7.y); aB.w += bfhi(v7.y);
    }
    for (; j + 2 <= cnt; j += 2) {
      int e0 = csr[r0 + j + 0], e1 = csr[r0 + j + 1];
      uint2 v0 = *(const uint2*)(hb + (size_t)(unsigned)e0 + (q << 3));
      uint2 v1 = *(const uint2*)(hb + (size_t)(unsigned)e1 + (q << 3));
      aA.x += bflo(v0.x); aA.y += bfhi(v0.x); aA.z += bflo(v0.y); aA.w += bfhi(v0.y);
      aB.x += bflo(v1.x); aB.y += bfhi(v1.x); aB.z += bflo(v1.y); aB.w += bfhi(v1.y);
    }
    if (j < cnt) {
      int e0 = csr[r0 + j];
      uint2 v0 = *(const uint2*)(hb + (size_t)(unsigned)e0 + (q << 3));
      aA.x += bflo(v0.x); aA.y += bfhi(v0.x); aA.z += bflo(v0.y); aA.w += bfhi(v0.y);
    }
    uint2 u = *(const uint2*)(hb + ((size_t)n << 7) + (q << 3));
    float4 a;
    a.x = aA.x + aB.x + bflo(u.x);
    a.y = aA.y + aB.y + bfhi(u.x);
    a.z = aA.z + aB.z + bflo(u.y);
    a.w = aA.w + aB.w + bfhi(u.y);
    float dn = dinv[n];
    a.x = a.x * dn + bval.x; a.y = a.y * dn + bval.y;
    a.z = a.z * dn + bval.z; a.w = a.w * dn + bval.w;
    uint2 o;
    o.x = f2bf(a.x) | (f2bf(a.y) << 16);
    o.y = f2bf(a.z) | (f2bf(a.w) << 16);
    *(uint2*)(ob + ((size_t)n << 7) + (q << 3)) = o;
    s.x += a.x; s.y += a.y; s.z += a.z; s.w += a.w;
    s2.x += a.x * a.x; s2.y += a.y * a.y;
    s2.z += a.z * a.z; s2.w += a.w * a.w;
  }

  __shared__ float rs[16][64];
  __shared__ float rs2[16][64];
  *(float4*)(&rs[w * 4 + g][q * 4]) = s;
  *(float4*)(&rs2[w * 4 + g][q * 4]) = s2;
  __syncthreads();
  int c = tid & 63;
  int r0_ = tid >> 6;
  float a = rs[r0_][c] + rs[r0_ + 4][c] + rs[r0_ + 8][c] + rs[r0_ + 12][c];
  float a2 = rs2[r0_][c] + rs2[r0_ + 4][c] + rs2[r0_ + 8][c] + rs2[r0_ + 12][c];
  __syncthreads();
  rs[r0_][c] = a;
  rs2[r0_][c] = a2;
  __syncthreads();
  if (r0_ == 0) {
    atomicAdd(&sums[c], rs[0][c] + rs[1][c] + rs[2][c] + rs[3][c]);
    atomicAdd(&sums[64 + c], rs2[0][c] + rs2[1][c] + rs2[2][c] + rs2[3][c]);
  }
}

// ---------------- pooling (batch sorted); BN3 inline; bf16 input ----------------

#define POOL_CHUNK 32
__global__ __launch_bounds__(256) void pool_k(
    const ushort_t* __restrict__ h, const float* __restrict__ sums,
    const float* __restrict__ gamma, const float* __restrict__ beta,
    const int* __restrict__ batch,
    float* __restrict__ psum, float* __restrict__ pcnt) {
  int w = threadIdx.x >> 6;
  int lane = threadIdx.x & 63;
  int start = (blockIdx.x * 4 + w) * POOL_CHUNK;
  if (start >= N_NODES) return;
  int end = min(start + POOL_CHUNK, N_NODES);
  float m = sums[lane] / (float)N_NODES;
  float v = sums[64 + lane] / (float)N_NODES - m * m;
  float sc = gamma[lane] * rsqrtf(v + BN_EPS);
  float sh = beta[lane] - m * sc;
  float acc = 0.f, cnt = 0.f;
  int cur = batch[start];
  for (int n = start; n < end; ++n) {
    int g = batch[n];
    if (g != cur) {
      atomicAdd(&psum[cur * 64 + lane], acc);
      if (lane == 0) atomicAdd(&pcnt[cur], cnt);
      acc = 0.f; cnt = 0.f; cur = g;
    }
    acc += bfu(h[(size_t)n * 64 + lane]) * sc + sh;
    cnt += 1.f;
  }
  atomicAdd(&psum[cur * 64 + lane], acc);
  if (lane == 0) atomicAdd(&pcnt[cur], cnt);
}

// ---------------- centroid classifier ----------------

__global__ void classify_k(const float* __restrict__ psum, const float* __restrict__ pcnt,
                           const float* __restrict__ cg_, const float* __restrict__ cm,
                           const float* __restrict__ temp, float* __restrict__ out) {
  int g = blockIdx.x;
  int t = threadIdx.x;
  __shared__ float emb[64];
  __shared__ float dist[208];
  if (t < 64) emb[t] = psum[g * 64 + t] / fmaxf(pcnt[g], 1.0f);
  __syncthreads();
  if (t < 197) {
    const float* C = (t < 5) ? (cg_ + t * 64) : (cm + (t - 5) * 64);
    float d = 0.f;
#pragma unroll 8
    for (int k = 0; k < 64; ++k) {
      float df = emb[k] - C[k];
      d += df * df;
    }
    dist[t] = d;
  }
  __syncthreads();
  float tv = temp[0];
  if (t == 64) {
    float m = dist[0];
    for (int j = 1; j < 5; ++j) m = fminf(m, dist[j]);
    out[g * 65] = -m / tv;
  }
  if (t < 64) {
    float m = fminf(dist[5 + t * 3], fminf(dist[5 + t * 3 + 1], dist[5 + t * 3 + 2]));
    out[g * 65 + 1 + t] = -m / tv;
  }
}

// ---------------- launch ----------------

extern "C" void kernel_launch(void* const* d_in, const int* in_sizes, int n_in,
                              void* d_out, int out_size, void* d_ws, size_t ws_size,
                              hipStream_t stream) {
  const float* x   = (const float*)d_in[0];
  const int* ei    = (const int*)d_in[1];
  const int* batch = (const int*)d_in[2];
  const float* W1 = (const float*)d_in[3];  const float* b1 = (const float*)d_in[4];
  const float* g1 = (const float*)d_in[5];  const float* be1 = (const float*)d_in[6];
  const float* W2 = (const float*)d_in[7];  const float* b2 = (const float*)d_in[8];
  const float* g2 = (const float*)d_in[9];  const float* be2 = (const float*)d_in[10];
  const float* W3 = (const float*)d_in[11]; const float* b3 = (const float*)d_in[12];
  const float* g3 = (const float*)d_in[13]; const float* be3 = (const float*)d_in[14];
  const float* cg_ = (const float*)d_in[15];
  const float* cm = (const float*)d_in[16];
  const float* temp = (const float*)d_in[17];
  float* out = (float*)d_out;

  char* ws = (char*)d_ws;
  size_t off = 0;
  auto alloc = [&](size_t bytes) -> void* {
    void* p = ws + off;
    off = (off + bytes + 255) & ~(size_t)255;
    return p;
  };
  int* gh        = (int*)alloc((size_t)NPB * 4);
  int* boff      = (int*)alloc((size_t)(NPB + 1) * 4);
  int* gcur      = (int*)alloc((size_t)NPB * 4);
  unsigned* tmp  = (unsigned*)alloc((size_t)N_EDGES * 4);
  int* csr       = (int*)alloc((size_t)N_EDGES * 4);
  int* rp4       = (int*)alloc((size_t)(4 * N_NODES + 1) * 4);
  float* dinv    = (float*)alloc((size_t)N_NODES * 4);
  ushort_t* hA   = (ushort_t*)alloc((size_t)N_NODES * 64 * 2);  // bf16 hs
  ushort_t* hB   = (ushort_t*)alloc((size_t)N_NODES * 64 * 2);  // bf16 h (pre-BN)
  float* sumsAll = (float*)alloc(3 * 128 * 4);
  float* psum    = (float*)alloc(64 * 64 * 4);
  float* pcnt    = (float*)alloc(64 * 4);

  hipMemsetAsync(gh, 0, (size_t)NPB * 4, stream);
  hipMemsetAsync(sumsAll, 0, 3 * 128 * 4, stream);
  hipMemsetAsync(psum, 0, 64 * 64 * 4, stream);
  hipMemsetAsync(pcnt, 0, 64 * 4, stream);

  const int NB_GEMM = (N_NODES + 63) / 64;   // 1563
  const int NB_POOL = (N_NODES + POOL_CHUNK * 4 - 1) / (POOL_CHUNK * 4);  // 782

  // CSR build
  ghist_k<<<512, 256, 0, stream>>>(ei, gh);
  gscan_k<<<1, 256, 0, stream>>>(gh, boff, gcur);
  part_k<<<PART_BLOCKS, 512, 0, stream>>>(ei, gcur, tmp);
  bwork_k<<<NPB, 512, 0, stream>>>(tmp, boff, rp4, dinv, csr);

  // layer 1 (MFMA, fp32 X -> bf16 frags)
  gemm_k<IN_DIM, false, false, false><<<NB_GEMM, 256, 0, stream>>>(x, W1, nullptr, nullptr, nullptr, dinv, hA, N_NODES);
  agg_k<<<AGG_BLOCKS, 256, 0, stream>>>(hA, dinv, rp4, csr, b1, hB, sumsAll);

  // layer 2 (BN1+ReLU inline from sums, bf16 input)
  gemm_k<HID, true, true, true><<<NB_GEMM, 256, 0, stream>>>(hB, W2, sumsAll, g1, be1, dinv, hA, N_NODES);
  agg_k<<<AGG_BLOCKS, 256, 0, stream>>>(hA, dinv, rp4, csr, b2, hB, sumsAll + 128);

  // layer 3 (BN2+ReLU inline from sums, bf16 input)
  gemm_k<HID, true, true, true><<<NB_GEMM, 256, 0, stream>>>(hB, W3, sumsAll + 128, g2, be2, dinv, hA, N_NODES);
  agg_k<<<AGG_BLOCKS, 256, 0, stream>>>(hA, dinv, rp4, csr, b3, hB, sumsAll + 256);

  // pool (BN3 inline from sums) + classify
  pool_k<<<NB_POOL, 256, 0, stream>>>(hB, sumsAll + 256, g3, be3, batch, psum, pcnt);
  classify_k<<<N_GRAPHS, 256, 0, stream>>>(psum, pcnt, cg_, cm, temp, out);
}

// Round 12
// 543.651 us; speedup vs baseline: 1.2734x; 1.0406x over previous
//
#include <hip/hip_runtime.h>
#include <math.h>

#define N_NODES 100000
#define N_EDGES 3200000
#define N_GRAPHS 64
#define IN_DIM 128
#define HID 64
#define BN_EPS 1e-5f

#define PSHIFT 9
#define PBS 512
#define NPB ((N_NODES + PBS - 1) / PBS)  // 196
#define PART_BLOCKS 256
#define CHUNK_E (N_EDGES / PART_BLOCKS)  // 12500 (multiple of 4)

#define QBOUND 25000
#define AGG_BLOCKS 2048

typedef unsigned short ushort_t;
typedef __attribute__((ext_vector_type(8))) short bf16x8;
typedef __attribute__((ext_vector_type(4))) float f32x4;

__device__ __forceinline__ float bflo(unsigned u) { return __uint_as_float(u << 16); }
__device__ __forceinline__ float bfhi(unsigned u) { return __uint_as_float(u & 0xFFFF0000u); }
__device__ __forceinline__ float bfu(ushort_t u) { return __uint_as_float((unsigned)u << 16); }
__device__ __forceinline__ unsigned f2bf(float f) {  // RNE
  unsigned u = __float_as_uint(f);
  return (u + 0x7FFFu + ((u >> 16) & 1u)) >> 16;
}

// ---------------- CSR build: two-level bucket sort, int4-vectorized ----------------

__global__ __launch_bounds__(256) void ghist_k(const int* __restrict__ ei,
                                               int* __restrict__ gh) {
  __shared__ int h[NPB];
  for (int i = threadIdx.x; i < NPB; i += 256) h[i] = 0;
  __syncthreads();
  const int4* d4 = (const int4*)(ei + N_EDGES);
  int n4 = N_EDGES / 4;
  int stride = gridDim.x * 256;
  for (int i = blockIdx.x * 256 + threadIdx.x; i < n4; i += stride) {
    int4 d = d4[i];
    atomicAdd(&h[d.x >> PSHIFT], 1);
    atomicAdd(&h[d.y >> PSHIFT], 1);
    atomicAdd(&h[d.z >> PSHIFT], 1);
    atomicAdd(&h[d.w >> PSHIFT], 1);
  }
  __syncthreads();
  for (int i = threadIdx.x; i < NPB; i += 256) {
    int v = h[i];
    if (v) atomicAdd(&gh[i], v);
  }
}

__global__ __launch_bounds__(256) void gscan_k(const int* __restrict__ gh,
                                               int* __restrict__ boff,
                                               int* __restrict__ gcur) {
  __shared__ int sa[256], sb[256];
  int t = threadIdx.x;
  int v = (t < NPB) ? gh[t] : 0;
  sa[t] = v;
  __syncthreads();
  int* src = sa; int* dst = sb;
  for (int o = 1; o < 256; o <<= 1) {
    dst[t] = src[t] + ((t >= o) ? src[t - o] : 0);
    __syncthreads();
    int* tmp = src; src = dst; dst = tmp;
  }
  if (t < NPB) {
    int excl = src[t] - v;
    boff[t] = excl;
    gcur[t] = excl;
    if (t == NPB - 1) boff[NPB] = src[t];
  }
}

__global__ __launch_bounds__(512) void part_k(const int* __restrict__ ei,
                                              int* __restrict__ gcur,
                                              unsigned* __restrict__ tmp) {
  __shared__ int lh[NPB];
  __shared__ int lcur[NPB];
  int t = threadIdx.x;
  for (int i = t; i < NPB; i += 512) lh[i] = 0;
  __syncthreads();
  int q0 = blockIdx.x * (CHUNK_E / 4);
  int q1 = q0 + CHUNK_E / 4;
  const int4* d4 = (const int4*)(ei + N_EDGES);
  const int4* s4 = (const int4*)ei;
  for (int i = q0 + t; i < q1; i += 512) {
    int4 d = d4[i];
    atomicAdd(&lh[d.x >> PSHIFT], 1);
    atomicAdd(&lh[d.y >> PSHIFT], 1);
    atomicAdd(&lh[d.z >> PSHIFT], 1);
    atomicAdd(&lh[d.w >> PSHIFT], 1);
  }
  __syncthreads();
  for (int i = t; i < NPB; i += 512) {
    int v = lh[i];
    lcur[i] = v ? atomicAdd(&gcur[i], v) : 0;
  }
  __syncthreads();
  for (int i = q0 + t; i < q1; i += 512) {
    int4 d = d4[i];
    int4 s = s4[i];
    int b0 = d.x >> PSHIFT, b1 = d.y >> PSHIFT, b2 = d.z >> PSHIFT, b3 = d.w >> PSHIFT;
    int p0 = atomicAdd(&lcur[b0], 1);
    int p1 = atomicAdd(&lcur[b1], 1);
    int p2 = atomicAdd(&lcur[b2], 1);
    int p3 = atomicAdd(&lcur[b3], 1);
    tmp[p0] = ((unsigned)(d.x & (PBS - 1)) << 17) | (unsigned)s.x;
    tmp[p1] = ((unsigned)(d.y & (PBS - 1)) << 17) | (unsigned)s.y;
    tmp[p2] = ((unsigned)(d.z & (PBS - 1)) << 17) | (unsigned)s.z;
    tmp[p3] = ((unsigned)(d.w & (PBS - 1)) << 17) | (unsigned)s.w;
  }
}

// fused per-bucket: histogram per (node, src-quartile) -> rp4/dinv -> place
__global__ __launch_bounds__(512) void bwork_k(
    const unsigned* __restrict__ tmp, const int* __restrict__ boff,
    int* __restrict__ rp4, float* __restrict__ dinv, int* __restrict__ csr) {
  int b = blockIdx.x;
  int base = boff[b], end = boff[b + 1];
  int t = threadIdx.x;
  __shared__ int cnt[PBS * 4];
  __shared__ int cur[PBS * 4];
  __shared__ int sa[PBS], sb[PBS];
  for (int i = t; i < PBS * 4; i += 512) cnt[i] = 0;
  __syncthreads();
  int a0 = (base + 3) & ~3;
  int a1 = end & ~3;
  if (a1 < a0) { a0 = end; a1 = end; }
  const uint4* t4 = (const uint4*)tmp;
#define HIST1(U) { unsigned u_ = (U); int nl_ = u_ >> 17; int s_ = u_ & 0x1FFFF; \
    int qq_ = (s_ >= QBOUND) + (s_ >= 2*QBOUND) + (s_ >= 3*QBOUND); \
    atomicAdd(&cnt[nl_ * 4 + qq_], 1); }
  if (base + t < a0) HIST1(tmp[base + t]);
  for (int i = a0 / 4 + t; i < a1 / 4; i += 512) {
    uint4 u = t4[i];
    HIST1(u.x) HIST1(u.y) HIST1(u.z) HIST1(u.w)
  }
  if (a1 + t < end) HIST1(tmp[a1 + t]);
#undef HIST1
  __syncthreads();
  int c0 = cnt[t * 4], c1 = cnt[t * 4 + 1], c2 = cnt[t * 4 + 2], c3 = cnt[t * 4 + 3];
  int tsum = c0 + c1 + c2 + c3;
  sa[t] = tsum;
  __syncthreads();
  int* src_ = sa; int* dst_ = sb;
  for (int o = 1; o < PBS; o <<= 1) {
    dst_[t] = src_[t] + ((t >= o) ? src_[t - o] : 0);
    __syncthreads();
    int* z = src_; src_ = dst_; dst_ = z;
  }
  int nb = src_[t] - tsum;
  int o0 = nb, o1 = nb + c0, o2 = nb + c0 + c1, o3 = nb + c0 + c1 + c2;
  cur[t * 4] = o0; cur[t * 4 + 1] = o1; cur[t * 4 + 2] = o2; cur[t * 4 + 3] = o3;
  int n = b * PBS + t;
  if (n < N_NODES) {
    rp4[4 * n] = base + o0;
    rp4[4 * n + 1] = base + o1;
    rp4[4 * n + 2] = base + o2;
    rp4[4 * n + 3] = base + o3;
    dinv[n] = rsqrtf((float)(tsum + 1));  // +1 self loop
    if (n == N_NODES - 1) rp4[4 * N_NODES] = base + nb + tsum;
  }
  __syncthreads();
#define PLACE1(U) { unsigned u_ = (U); int nl_ = u_ >> 17; int s_ = u_ & 0x1FFFF; \
    int qq_ = (s_ >= QBOUND) + (s_ >= 2*QBOUND) + (s_ >= 3*QBOUND); \
    int p_ = atomicAdd(&cur[nl_ * 4 + qq_], 1); \
    csr[base + p_] = s_ << 7; }
  if (base + t < a0) PLACE1(tmp[base + t]);
  for (int i = a0 / 4 + t; i < a1 / 4; i += 512) {
    uint4 u = t4[i];
    PLACE1(u.x) PLACE1(u.y) PLACE1(u.z) PLACE1(u.w)
  }
  if (a1 + t < end) PLACE1(tmp[a1 + t]);
#undef PLACE1
}

// ---------------- MFMA GEMM: hs[n][c] = dinv[n] * (BN(X)[n] @ W)[c] -> bf16 ----------------

template <int K, bool XBF16, bool APPLY, bool RELU>
__global__ __launch_bounds__(256) void gemm_k(
    const void* __restrict__ Xv, const float* __restrict__ W,
    const float* __restrict__ sums, const float* __restrict__ gamma,
    const float* __restrict__ beta, const float* __restrict__ dinv,
    ushort_t* __restrict__ out, int nrows) {
  __shared__ ushort_t wt[64 * K];   // wt[n][k] bf16
  __shared__ float scs[128], shs[128];
  __shared__ float redo[64 * 65];   // D repack, padded
  const int tid = threadIdx.x;
  const int wv = tid >> 6;
  const int lane = tid & 63;
  const int lm = lane & 15;
  const int lq = lane >> 4;

  for (int idx = tid; idx < K * 64; idx += 256) {
    int k = idx >> 6, c = idx & 63;      // W[k][c]
    wt[c * K + k] = (ushort_t)f2bf(W[idx]);
  }
  if (APPLY) {
    for (int k = tid; k < K; k += 256) {
      float m = sums[k] / (float)N_NODES;
      float v = sums[64 + k] / (float)N_NODES - m * m;
      float s = gamma[k] * rsqrtf(v + BN_EPS);
      scs[k] = s;
      shs[k] = beta[k] - m * s;
    }
  }
  __syncthreads();

  const int rowbase = blockIdx.x * 64;
  const int grow = rowbase + wv * 16 + lm;
  const bool valid = grow < nrows;
  f32x4 acc0 = {0.f, 0.f, 0.f, 0.f};
  f32x4 acc1 = acc0, acc2 = acc0, acc3 = acc0;

#pragma unroll
  for (int k0 = 0; k0 < K; k0 += 32) {
    int kbase = k0 + lq * 8;
    bf16x8 a = {0, 0, 0, 0, 0, 0, 0, 0};
    if (valid) {
      if (XBF16) {
        uint4 u = *(const uint4*)((const char*)Xv + ((size_t)grow * 64 + kbase) * 2);
        if (APPLY) {
          float4 sc0 = *(const float4*)&scs[kbase];
          float4 sc1 = *(const float4*)&scs[kbase + 4];
          float4 sh0 = *(const float4*)&shs[kbase];
          float4 sh1 = *(const float4*)&shs[kbase + 4];
          float f0 = bflo(u.x) * sc0.x + sh0.x, f1 = bfhi(u.x) * sc0.y + sh0.y;
          float f2 = bflo(u.y) * sc0.z + sh0.z, f3 = bfhi(u.y) * sc0.w + sh0.w;
          float f4 = bflo(u.z) * sc1.x + sh1.x, f5 = bfhi(u.z) * sc1.y + sh1.y;
          float f6 = bflo(u.w) * sc1.z + sh1.z, f7 = bfhi(u.w) * sc1.w + sh1.w;
          if (RELU) {
            f0 = fmaxf(f0, 0.f); f1 = fmaxf(f1, 0.f);
            f2 = fmaxf(f2, 0.f); f3 = fmaxf(f3, 0.f);
            f4 = fmaxf(f4, 0.f); f5 = fmaxf(f5, 0.f);
            f6 = fmaxf(f6, 0.f); f7 = fmaxf(f7, 0.f);
          }
          a[0] = (short)f2bf(f0); a[1] = (short)f2bf(f1);
          a[2] = (short)f2bf(f2); a[3] = (short)f2bf(f3);
          a[4] = (short)f2bf(f4); a[5] = (short)f2bf(f5);
          a[6] = (short)f2bf(f6); a[7] = (short)f2bf(f7);
        } else {
          a = *(const bf16x8*)&u;
        }
      } else {
        const float* xp = (const float*)Xv + (size_t)grow * K + kbase;
        float4 xa = *(const float4*)xp;
        float4 xb = *(const float4*)(xp + 4);
        a[0] = (short)f2bf(xa.x); a[1] = (short)f2bf(xa.y);
        a[2] = (short)f2bf(xa.z); a[3] = (short)f2bf(xa.w);
        a[4] = (short)f2bf(xb.x); a[5] = (short)f2bf(xb.y);
        a[6] = (short)f2bf(xb.z); a[7] = (short)f2bf(xb.w);
      }
    }
    bf16x8 b0 = *(const bf16x8*)(wt + (0 + lm) * K + kbase);
    bf16x8 b1 = *(const bf16x8*)(wt + (16 + lm) * K + kbase);
    bf16x8 b2 = *(const bf16x8*)(wt + (32 + lm) * K + kbase);
    bf16x8 b3 = *(const bf16x8*)(wt + (48 + lm) * K + kbase);
    acc0 = __builtin_amdgcn_mfma_f32_16x16x32_bf16(a, b0, acc0, 0, 0, 0);
    acc1 = __builtin_amdgcn_mfma_f32_16x16x32_bf16(a, b1, acc1, 0, 0, 0);
    acc2 = __builtin_amdgcn_mfma_f32_16x16x32_bf16(a, b2, acc2, 0, 0, 0);
    acc3 = __builtin_amdgcn_mfma_f32_16x16x32_bf16(a, b3, acc3, 0, 0, 0);
  }

#pragma unroll
  for (int r = 0; r < 4; ++r) {
    int rr = wv * 16 + lq * 4 + r;
    redo[rr * 65 + lm] = acc0[r];
    redo[rr * 65 + 16 + lm] = acc1[r];
    redo[rr * 65 + 32 + lm] = acc2[r];
    redo[rr * 65 + 48 + lm] = acc3[r];
  }
  __syncthreads();
  {
    int r = tid >> 2;
    int cq = (tid & 3) * 16;
    int gr = rowbase + r;
    if (gr < nrows) {
      float dn = dinv[gr];
      const float* sp = &redo[r * 65 + cq];
      unsigned p[8];
#pragma unroll
      for (int i = 0; i < 8; ++i)
        p[i] = f2bf(sp[2 * i] * dn) | (f2bf(sp[2 * i + 1] * dn) << 16);
      char* ob = (char*)out + ((size_t)gr * 64 + cq) * 2;
      *(uint4*)ob = make_uint4(p[0], p[1], p[2], p[3]);
      *(uint4*)(ob + 16) = make_uint4(p[4], p[5], p[6], p[7]);
    }
  }
}

// ---------------- aggregation: x8 unroll + software-pipelined csr prefetch ----------------
// Batch k's gathers are issued, THEN batch k+1's csr entries are loaded, THEN
// we wait on the gathers (compiler emits vmcnt(8)) -> the csr L2 round-trip
// overlaps the gather round-trip instead of serializing with it.

__global__ __launch_bounds__(256) void agg_k(
    const ushort_t* __restrict__ hs, const float* __restrict__ dinv,
    const int* __restrict__ rp4, const int* __restrict__ csr,
    const float* __restrict__ bias, ushort_t* __restrict__ out,
    float* __restrict__ sums) {
  const int tid = threadIdx.x;
  const int w = tid >> 6;
  const int lane = tid & 63;
  const int g = lane >> 4;     // node slot 0..3
  const int q = lane & 15;     // feature quad
  const char* hb = (const char*)hs;
  char* ob = (char*)out;

  float4 bval = *(const float4*)(bias + q * 4);
  float4 s = make_float4(0.f, 0.f, 0.f, 0.f);
  float4 s2 = make_float4(0.f, 0.f, 0.f, 0.f);

  for (int n = blockIdx.x * 16 + w * 4 + g; n < N_NODES; n += AGG_BLOCKS * 16) {
    int r0 = rp4[4 * n];
    int cnt = rp4[4 * n + 4] - r0;
    uint2 selfu = *(const uint2*)(hb + ((size_t)n << 7) + (q << 3));  // issue early
    float4 aA = {0, 0, 0, 0}, aB = {0, 0, 0, 0};
    int j = 0;
    if (cnt >= 8) {
      int e0 = csr[r0 + 0], e1 = csr[r0 + 1], e2 = csr[r0 + 2], e3 = csr[r0 + 3];
      int e4 = csr[r0 + 4], e5 = csr[r0 + 5], e6 = csr[r0 + 6], e7 = csr[r0 + 7];
      for (; j + 16 <= cnt; j += 8) {
        uint2 v0 = *(const uint2*)(hb + (size_t)(unsigned)e0 + (q << 3));
        uint2 v1 = *(const uint2*)(hb + (size_t)(unsigned)e1 + (q << 3));
        uint2 v2 = *(const uint2*)(hb + (size_t)(unsigned)e2 + (q << 3));
        uint2 v3 = *(const uint2*)(hb + (size_t)(unsigned)e3 + (q << 3));
        uint2 v4 = *(const uint2*)(hb + (size_t)(unsigned)e4 + (q << 3));
        uint2 v5 = *(const uint2*)(hb + (size_t)(unsigned)e5 + (q << 3));
        uint2 v6 = *(const uint2*)(hb + (size_t)(unsigned)e6 + (q << 3));
        uint2 v7 = *(const uint2*)(hb + (size_t)(unsigned)e7 + (q << 3));
        // prefetch next csr batch while gathers are in flight
        e0 = csr[r0 + j + 8];  e1 = csr[r0 + j + 9];
        e2 = csr[r0 + j + 10]; e3 = csr[r0 + j + 11];
        e4 = csr[r0 + j + 12]; e5 = csr[r0 + j + 13];
        e6 = csr[r0 + j + 14]; e7 = csr[r0 + j + 15];
        aA.x += bflo(v0.x); aA.y += bfhi(v0.x); aA.z += bflo(v0.y); aA.w += bfhi(v0.y);
        aB.x += bflo(v1.x); aB.y += bfhi(v1.x); aB.z += bflo(v1.y); aB.w += bfhi(v1.y);
        aA.x += bflo(v2.x); aA.y += bfhi(v2.x); aA.z += bflo(v2.y); aA.w += bfhi(v2.y);
        aB.x += bflo(v3.x); aB.y += bfhi(v3.x); aB.z += bflo(v3.y); aB.w += bfhi(v3.y);
        aA.x += bflo(v4.x); aA.y += bfhi(v4.x); aA.z += bflo(v4.y); aA.w += bfhi(v4.y);
        aB.x += bflo(v5.x); aB.y += bfhi(v5.x); aB.z += bflo(v5.y); aB.w += bfhi(v5.y);
        aA.x += bflo(v6.x); aA.y += bfhi(v6.x); aA.z += bflo(v6.y); aA.w += bfhi(v6.y);
        aB.x += bflo(v7.x); aB.y += bfhi(v7.x); aB.z += bflo(v7.y); aB.w += bfhi(v7.y);
      }
      {  // final preloaded batch
        uint2 v0 = *(const uint2*)(hb + (size_t)(unsigned)e0 + (q << 3));
        uint2 v1 = *(const uint2*)(hb + (size_t)(unsigned)e1 + (q << 3));
        uint2 v2 = *(const uint2*)(hb + (size_t)(unsigned)e2 + (q << 3));
        uint2 v3 = *(const uint2*)(hb + (size_t)(unsigned)e3 + (q << 3));
        uint2 v4 = *(const uint2*)(hb + (size_t)(unsigned)e4 + (q << 3));
        uint2 v5 = *(const uint2*)(hb + (size_t)(unsigned)e5 + (q << 3));
        uint2 v6 = *(const uint2*)(hb + (size_t)(unsigned)e6 + (q << 3));
        uint2 v7 = *(const uint2*)(hb + (size_t)(unsigned)e7 + (q << 3));
        aA.x += bflo(v0.x); aA.y += bfhi(v0.x); aA.z += bflo(v0.y); aA.w += bfhi(v0.y);
        aB.x += bflo(v1.x); aB.y += bfhi(v1.x); aB.z += bflo(v1.y); aB.w += bfhi(v1.y);
        aA.x += bflo(v2.x); aA.y += bfhi(v2.x); aA.z += bflo(v2.y); aA.w += bfhi(v2.y);
        aB.x += bflo(v3.x); aB.y += bfhi(v3.x); aB.z += bflo(v3.y); aB.w += bfhi(v3.y);
        aA.x += bflo(v4.x); aA.y += bfhi(v4.x); aA.z += bflo(v4.y); aA.w += bfhi(v4.y);
        aB.x += bflo(v5.x); aB.y += bfhi(v5.x); aB.z += bflo(v5.y); aB.w += bfhi(v5.y);
        aA.x += bflo(v6.x); aA.y += bfhi(v6.x); aA.z += bflo(v6.y); aA.w += bfhi(v6.y);
        aB.x += bflo(v7.x); aB.y += bfhi(v7.x); aB.z += bflo(v7.y); aB.w += bfhi(v7.y);
        j += 8;
      }
    }
    for (; j + 2 <= cnt; j += 2) {
      int e0 = csr[r0 + j + 0], e1 = csr[r0 + j + 1];
      uint2 v0 = *(const uint2*)(hb + (size_t)(unsigned)e0 + (q << 3));
      uint2 v1 = *(const uint2*)(hb + (size_t)(unsigned)e1 + (q << 3));
      aA.x += bflo(v0.x); aA.y += bfhi(v0.x); aA.z += bflo(v0.y); aA.w += bfhi(v0.y);
      aB.x += bflo(v1.x); aB.y += bfhi(v1.x); aB.z += bflo(v1.y); aB.w += bfhi(v1.y);
    }
    if (j < cnt) {
      int e0 = csr[r0 + j];
      uint2 v0 = *(const uint2*)(hb + (size_t)(unsigned)e0 + (q << 3));
      aA.x += bflo(v0.x); aA.y += bfhi(v0.x); aA.z += bflo(v0.y); aA.w += bfhi(v0.y);
    }
    float4 a;
    a.x = aA.x + aB.x + bflo(selfu.x);
    a.y = aA.y + aB.y + bfhi(selfu.x);
    a.z = aA.z + aB.z + bflo(selfu.y);
    a.w = aA.w + aB.w + bfhi(selfu.y);
    float dn = dinv[n];
    a.x = a.x * dn + bval.x; a.y = a.y * dn + bval.y;
    a.z = a.z * dn + bval.z; a.w = a.w * dn + bval.w;
    uint2 o;
    o.x = f2bf(a.x) | (f2bf(a.y) << 16);
    o.y = f2bf(a.z) | (f2bf(a.w) << 16);
    *(uint2*)(ob + ((size_t)n << 7) + (q << 3)) = o;
    s.x += a.x; s.y += a.y; s.z += a.z; s.w += a.w;
    s2.x += a.x * a.x; s2.y += a.y * a.y;
    s2.z += a.z * a.z; s2.w += a.w * a.w;
  }

  __shared__ float rs[16][64];
  __shared__ float rs2[16][64];
  *(float4*)(&rs[w * 4 + g][q * 4]) = s;
  *(float4*)(&rs2[w * 4 + g][q * 4]) = s2;
  __syncthreads();
  int c = tid & 63;
  int r0_ = tid >> 6;
  float a = rs[r0_][c] + rs[r0_ + 4][c] + rs[r0_ + 8][c] + rs[r0_ + 12][c];
  float a2 = rs2[r0_][c] + rs2[r0_ + 4][c] + rs2[r0_ + 8][c] + rs2[r0_ + 12][c];
  __syncthreads();
  rs[r0_][c] = a;
  rs2[r0_][c] = a2;
  __syncthreads();
  if (r0_ == 0) {
    atomicAdd(&sums[c], rs[0][c] + rs[1][c] + rs[2][c] + rs[3][c]);
    atomicAdd(&sums[64 + c], rs2[0][c] + rs2[1][c] + rs2[2][c] + rs2[3][c]);
  }
}

// ---------------- pooling (batch sorted); BN3 inline; bf16 input ----------------

#define POOL_CHUNK 32
__global__ __launch_bounds__(256) void pool_k(
    const ushort_t* __restrict__ h, const float* __restrict__ sums,
    const float* __restrict__ gamma, const float* __restrict__ beta,
    const int* __restrict__ batch,
    float* __restrict__ psum, float* __restrict__ pcnt) {
  int w = threadIdx.x >> 6;
  int lane = threadIdx.x & 63;
  int start = (blockIdx.x * 4 + w) * POOL_CHUNK;
  if (start >= N_NODES) return;
  int end = min(start + POOL_CHUNK, N_NODES);
  float m = sums[lane] / (float)N_NODES;
  float v = sums[64 + lane] / (float)N_NODES - m * m;
  float sc = gamma[lane] * rsqrtf(v + BN_EPS);
  float sh = beta[lane] - m * sc;
  float acc = 0.f, cnt = 0.f;
  int cur = batch[start];
  for (int n = start; n < end; ++n) {
    int g = batch[n];
    if (g != cur) {
      atomicAdd(&psum[cur * 64 + lane], acc);
      if (lane == 0) atomicAdd(&pcnt[cur], cnt);
      acc = 0.f; cnt = 0.f; cur = g;
    }
    acc += bfu(h[(size_t)n * 64 + lane]) * sc + sh;
    cnt += 1.f;
  }
  atomicAdd(&psum[cur * 64 + lane], acc);
  if (lane == 0) atomicAdd(&pcnt[cur], cnt);
}

// ---------------- centroid classifier ----------------

__global__ void classify_k(const float* __restrict__ psum, const float* __restrict__ pcnt,
                           const float* __restrict__ cg_, const float* __restrict__ cm,
                           const float* __restrict__ temp, float* __restrict__ out) {
  int g = blockIdx.x;
  int t = threadIdx.x;
  __shared__ float emb[64];
  __shared__ float dist[208];
  if (t < 64) emb[t] = psum[g * 64 + t] / fmaxf(pcnt[g], 1.0f);
  __syncthreads();
  if (t < 197) {
    const float* C = (t < 5) ? (cg_ + t * 64) : (cm + (t - 5) * 64);
    float d = 0.f;
#pragma unroll 8
    for (int k = 0; k < 64; ++k) {
      float df = emb[k] - C[k];
      d += df * df;
    }
    dist[t] = d;
  }
  __syncthreads();
  float tv = temp[0];
  if (t == 64) {
    float m = dist[0];
    for (int j = 1; j < 5; ++j) m = fminf(m, dist[j]);
    out[g * 65] = -m / tv;
  }
  if (t < 64) {
    float m = fminf(dist[5 + t * 3], fminf(dist[5 + t * 3 + 1], dist[5 + t * 3 + 2]));
    out[g * 65 + 1 + t] = -m / tv;
  }
}

// ---------------- launch ----------------

extern "C" void kernel_launch(void* const* d_in, const int* in_sizes, int n_in,
                              void* d_out, int out_size, void* d_ws, size_t ws_size,
                              hipStream_t stream) {
  const float* x   = (const float*)d_in[0];
  const int* ei    = (const int*)d_in[1];
  const int* batch = (const int*)d_in[2];
  const float* W1 = (const float*)d_in[3];  const float* b1 = (const float*)d_in[4];
  const float* g1 = (const float*)d_in[5];  const float* be1 = (const float*)d_in[6];
  const float* W2 = (const float*)d_in[7];  const float* b2 = (const float*)d_in[8];
  const float* g2 = (const float*)d_in[9];  const float* be2 = (const float*)d_in[10];
  const float* W3 = (const float*)d_in[11]; const float* b3 = (const float*)d_in[12];
  const float* g3 = (const float*)d_in[13]; const float* be3 = (const float*)d_in[14];
  const float* cg_ = (const float*)d_in[15];
  const float* cm = (const float*)d_in[16];
  const float* temp = (const float*)d_in[17];
  float* out = (float*)d_out;

  char* ws = (char*)d_ws;
  size_t off = 0;
  auto alloc = [&](size_t bytes) -> void* {
    void* p = ws + off;
    off = (off + bytes + 255) & ~(size_t)255;
    return p;
  };
  // zero-init block first -> single memset
  int* gh        = (int*)alloc((size_t)NPB * 4);
  float* sumsAll = (float*)alloc(3 * 128 * 4);
  float* psum    = (float*)alloc(64 * 64 * 4);
  float* pcnt    = (float*)alloc(64 * 4);
  size_t zero_end = off;
  int* boff      = (int*)alloc((size_t)(NPB + 1) * 4);
  int* gcur      = (int*)alloc((size_t)NPB * 4);
  unsigned* tmp  = (unsigned*)alloc((size_t)N_EDGES * 4);
  int* csr       = (int*)alloc((size_t)N_EDGES * 4);
  int* rp4       = (int*)alloc((size_t)(4 * N_NODES + 1) * 4);
  float* dinv    = (float*)alloc((size_t)N_NODES * 4);
  ushort_t* hA   = (ushort_t*)alloc((size_t)N_NODES * 64 * 2);  // bf16 hs
  ushort_t* hB   = (ushort_t*)alloc((size_t)N_NODES * 64 * 2);  // bf16 h (pre-BN)

  hipMemsetAsync(ws, 0, zero_end, stream);

  const int NB_GEMM = (N_NODES + 63) / 64;   // 1563
  const int NB_POOL = (N_NODES + POOL_CHUNK * 4 - 1) / (POOL_CHUNK * 4);  // 782

  // CSR build
  ghist_k<<<512, 256, 0, stream>>>(ei, gh);
  gscan_k<<<1, 256, 0, stream>>>(gh, boff, gcur);
  part_k<<<PART_BLOCKS, 512, 0, stream>>>(ei, gcur, tmp);
  bwork_k<<<NPB, 512, 0, stream>>>(tmp, boff, rp4, dinv, csr);

  // layer 1 (MFMA, fp32 X -> bf16 frags)
  gemm_k<IN_DIM, false, false, false><<<NB_GEMM, 256, 0, stream>>>(x, W1, nullptr, nullptr, nullptr, dinv, hA, N_NODES);
  agg_k<<<AGG_BLOCKS, 256, 0, stream>>>(hA, dinv, rp4, csr, b1, hB, sumsAll);

  // layer 2 (BN1+ReLU inline from sums, bf16 input)
  gemm_k<HID, true, true, true><<<NB_GEMM, 256, 0, stream>>>(hB, W2, sumsAll, g1, be1, dinv, hA, N_NODES);
  agg_k<<<AGG_BLOCKS, 256, 0, stream>>>(hA, dinv, rp4, csr, b2, hB, sumsAll + 128);

  // layer 3 (BN2+ReLU inline from sums, bf16 input)
  gemm_k<HID, true, true, true><<<NB_GEMM, 256, 0, stream>>>(hB, W3, sumsAll + 128, g2, be2, dinv, hA, N_NODES);
  agg_k<<<AGG_BLOCKS, 256, 0, stream>>>(hA, dinv, rp4, csr, b3, hB, sumsAll + 256);

  // pool (BN3 inline from sums) + classify
  pool_k<<<NB_POOL, 256, 0, stream>>>(hB, sumsAll + 256, g3, be3, batch, psum, pcnt);
  classify_k<<<N_GRAPHS, 256, 0, stream>>>(psum, pcnt, cg_, cm, temp, out);
}